// Round 1
// baseline (1192.899 us; speedup 1.0000x reference)
//
#include <hip/hip_runtime.h>
#include <hip/hip_bf16.h>
#include <stdint.h>

// Sparse MoE: N=8192 tokens, H=1024, E=8 experts, top-K=2, FF=4096.
// Strategy: router -> per-expert token lists -> grouped f16 MFMA GEMMs
// (only the selected 2 experts per token => 275 GFLOP instead of 1.1 TFLOP).

#define NTOK 8192
#define HD   1024
#define NE   8
#define FF   4096

typedef float  f32x4 __attribute__((ext_vector_type(4)));
typedef _Float16 half8 __attribute__((ext_vector_type(8)));
typedef _Float16 half4 __attribute__((ext_vector_type(4)));

#define AS1 __attribute__((address_space(1)))
#define AS3 __attribute__((address_space(3)))

__device__ __forceinline__ void gload16(const void* g, void* l) {
  __builtin_amdgcn_global_load_lds((AS1 void*)g, (AS3 void*)l, 16, 0, 0);
}

// ---------------- prep: convert x to f16 ----------------
__global__ __launch_bounds__(256) void convx_k(const float* __restrict__ x,
                                               _Float16* __restrict__ xh) {
  int i = blockIdx.x * 256 + threadIdx.x;   // 8192*1024/4 = 2097152 float4s
  float4 v = ((const float4*)x)[i];
  half4 h = {(_Float16)v.x, (_Float16)v.y, (_Float16)v.z, (_Float16)v.w};
  ((half4*)xh)[i] = h;
}

// ---------------- prep: convert + transpose weights ----------------
// src: [E][R][C] f32 row-major  ->  dst: [E][C][R] f16 row-major
__global__ __launch_bounds__(256) void transc_k(const float* __restrict__ src,
                                                _Float16* __restrict__ dst,
                                                int R, int C) {
  __shared__ float t[64][65];
  const int e = blockIdx.z;
  const size_t eb = (size_t)e * R * C;
  const int r0 = blockIdx.y * 64, c0 = blockIdx.x * 64;
  const int tid = threadIdx.x;
#pragma unroll
  for (int i = 0; i < 4; ++i) {
    int idx = tid + i * 256;
    int r = idx >> 4, c = (idx & 15) * 4;
    float4 v = *(const float4*)(src + eb + (size_t)(r0 + r) * C + (c0 + c));
    t[r][c] = v.x; t[r][c + 1] = v.y; t[r][c + 2] = v.z; t[r][c + 3] = v.w;
  }
  __syncthreads();
#pragma unroll
  for (int i = 0; i < 4; ++i) {
    int idx = tid + i * 256;
    int cr = idx >> 4, r4 = (idx & 15) * 4;
    half4 o = {(_Float16)t[r4][cr], (_Float16)t[r4 + 1][cr],
               (_Float16)t[r4 + 2][cr], (_Float16)t[r4 + 3][cr]};
    *(half4*)(dst + eb + (size_t)(c0 + cr) * R + (r0 + r4)) = o;
  }
}

// ---------------- router: logits -> softmax -> top-2 -> expert lists ----------------
__global__ __launch_bounds__(256) void router_k(const float* __restrict__ x,
                                                const float* __restrict__ grad,
                                                const float* __restrict__ Wr,
                                                const float* __restrict__ br,
                                                int* __restrict__ counts,
                                                int* __restrict__ tokL,
                                                float* __restrict__ wL) {
  const int lane = threadIdx.x & 63;
  const int n = blockIdx.x * 4 + (threadIdx.x >> 6);
  float acc[8] = {0.f, 0.f, 0.f, 0.f, 0.f, 0.f, 0.f, 0.f};
  const float* xr = x + (size_t)n * HD;
#pragma unroll 4
  for (int i = 0; i < 16; ++i) {
    float xv = xr[i * 64 + lane];
    const float* wr = Wr + (size_t)(i * 64 + lane) * NE;
    float4 w0 = *(const float4*)wr;
    float4 w1 = *(const float4*)(wr + 4);
    acc[0] += xv * w0.x; acc[1] += xv * w0.y; acc[2] += xv * w0.z; acc[3] += xv * w0.w;
    acc[4] += xv * w1.x; acc[5] += xv * w1.y; acc[6] += xv * w1.z; acc[7] += xv * w1.w;
  }
#pragma unroll
  for (int off = 32; off > 0; off >>= 1)
#pragma unroll
    for (int e = 0; e < 8; ++e) acc[e] += __shfl_xor(acc[e], off, 64);
  if (lane == 0) {
    float gv = grad[n];
    float lg[8];
#pragma unroll
    for (int e = 0; e < 8; ++e) lg[e] = acc[e] + gv * Wr[HD * NE + e] + br[e];
    float m = lg[0];
#pragma unroll
    for (int e = 1; e < 8; ++e) m = fmaxf(m, lg[e]);
    float s = 0.f, p[8];
#pragma unroll
    for (int e = 0; e < 8; ++e) { p[e] = expf(lg[e] - m); s += p[e]; }
    int i1 = 0;
#pragma unroll
    for (int e = 1; e < 8; ++e) if (lg[e] > lg[i1]) i1 = e;
    int i2 = (i1 == 0) ? 1 : 0;
#pragma unroll
    for (int e = 0; e < 8; ++e) if (e != i1 && lg[e] > lg[i2]) i2 = e;
    float inv = 1.0f / s;
    int p1 = atomicAdd(&counts[i1], 1);
    tokL[i1 * NTOK + p1] = n; wL[i1 * NTOK + p1] = p[i1] * inv;
    int p2 = atomicAdd(&counts[i2], 1);
    tokL[i2 * NTOK + p2] = n; wL[i2 * NTOK + p2] = p[i2] * inv;
  }
}

__global__ void prefix_k(const int* __restrict__ counts, int* __restrict__ base) {
  if (threadIdx.x == 0) {
    int s = 0;
    for (int e = 0; e < NE; ++e) { base[e] = s; s += counts[e]; }
  }
}

// ---------------- GEMM1: h = gelu(Xg @ W1 + b1), gathered rows, f16 out ----------------
// A: xh gathered rows [cnt][1024]; B: w1t [E][4096][1024]; tile 128x128, BK=64.
__global__ __launch_bounds__(256) void gemm1_k(const _Float16* __restrict__ xh,
                                               const _Float16* __restrict__ w1t,
                                               const float* __restrict__ b1,
                                               const int* __restrict__ tokL,
                                               const int* __restrict__ counts,
                                               const int* __restrict__ base,
                                               _Float16* __restrict__ hbuf) {
  const int e = blockIdx.z;
  const int cnt = counts[e];
  const int m0 = blockIdx.y * 128;
  if (m0 >= cnt) return;
  const int n0 = blockIdx.x * 128;
  const int hb = base[e];

  __shared__ __align__(16) char smem[32768];
  char* Abase = smem;
  char* Bbase = smem + 16384;

  const int tid = threadIdx.x;
  const int lane = tid & 63;
  const int wid = tid >> 6;
  const int wm = wid >> 1, wn = wid & 1;

  // staging: thread covers rows srow+32c, fixed swizzled k-chunk kk (elements)
  const int srow = tid >> 3;
  const int kk = ((tid & 7) ^ (srow & 7)) << 3;
  const _Float16* aSrc[4];
  const _Float16* bSrc[4];
#pragma unroll
  for (int c = 0; c < 4; ++c) {
    int r = srow + 32 * c;
    int gm = m0 + r; if (gm >= cnt) gm = cnt - 1;
    int t = tokL[e * NTOK + gm];
    aSrc[c] = xh + (size_t)t * HD + kk;
    bSrc[c] = w1t + ((size_t)e * FF + n0 + r) * HD + kk;
  }
  char* aDst[4];
  char* bDst[4];
#pragma unroll
  for (int c = 0; c < 4; ++c) {
    aDst[c] = Abase + (tid & 192) * 16 + c * 4096;  // wave-uniform base; HW adds lane*16
    bDst[c] = Bbase + (tid & 192) * 16 + c * 4096;
  }

  f32x4 acc[4][4] = {};
  const int lr = lane & 15, lk = lane >> 4;

  for (int kt = 0; kt < HD / 64; ++kt) {
#pragma unroll
    for (int c = 0; c < 4; ++c) {
      gload16(aSrc[c], aDst[c]);
      gload16(bSrc[c], bDst[c]);
      aSrc[c] += 64; bSrc[c] += 64;
    }
    asm volatile("s_waitcnt vmcnt(0)");
    __syncthreads();
#pragma unroll
    for (int k2 = 0; k2 < 2; ++k2) {
      half8 a[4], b[4];
#pragma unroll
      for (int mf = 0; mf < 4; ++mf) {
        int row = wm * 64 + mf * 16 + lr;
        int off = row * 128 + (((k2 * 64) + (lk << 4)) ^ ((row & 7) << 4));
        a[mf] = *(const half8*)(Abase + off);
      }
#pragma unroll
      for (int nf = 0; nf < 4; ++nf) {
        int row = wn * 64 + nf * 16 + lr;
        int off = row * 128 + (((k2 * 64) + (lk << 4)) ^ ((row & 7) << 4));
        b[nf] = *(const half8*)(Bbase + off);
      }
#pragma unroll
      for (int mf = 0; mf < 4; ++mf)
#pragma unroll
        for (int nf = 0; nf < 4; ++nf)
          acc[mf][nf] = __builtin_amdgcn_mfma_f32_16x16x32_f16(a[mf], b[nf], acc[mf][nf], 0, 0, 0);
    }
    __syncthreads();
  }

  // epilogue: bias + exact-erf GELU -> f16 h
#pragma unroll
  for (int nf = 0; nf < 4; ++nf) {
    int n = n0 + wn * 64 + nf * 16 + lr;
    float bias = b1[(size_t)e * FF + n];
#pragma unroll
    for (int mf = 0; mf < 4; ++mf) {
      int mb = wm * 64 + mf * 16 + lk * 4;
#pragma unroll
      for (int j = 0; j < 4; ++j) {
        int gm = m0 + mb + j;
        if (gm < cnt) {
          float v = acc[mf][nf][j] + bias;
          v = 0.5f * v * (1.0f + erff(v * 0.70710678118654752f));
          hbuf[(size_t)(hb + gm) * FF + n] = (_Float16)v;
        }
      }
    }
  }
}

// ---------------- GEMM2: out += p * (h @ W2 + b2), atomic scatter ----------------
__global__ __launch_bounds__(256) void gemm2_k(const _Float16* __restrict__ hbuf,
                                               const _Float16* __restrict__ w2t,
                                               const float* __restrict__ b2,
                                               const int* __restrict__ tokL,
                                               const float* __restrict__ wL,
                                               const int* __restrict__ counts,
                                               const int* __restrict__ base,
                                               float* __restrict__ out) {
  const int e = blockIdx.z;
  const int cnt = counts[e];
  const int m0 = blockIdx.y * 128;
  if (m0 >= cnt) return;
  const int n0 = blockIdx.x * 128;
  const int hb = base[e];

  __shared__ __align__(16) char smem[32768];
  char* Abase = smem;
  char* Bbase = smem + 16384;

  const int tid = threadIdx.x;
  const int lane = tid & 63;
  const int wid = tid >> 6;
  const int wm = wid >> 1, wn = wid & 1;

  const int srow = tid >> 3;
  const int kk = ((tid & 7) ^ (srow & 7)) << 3;
  const _Float16* aSrc[4];
  const _Float16* bSrc[4];
#pragma unroll
  for (int c = 0; c < 4; ++c) {
    int r = srow + 32 * c;
    int gm = m0 + r; if (gm >= cnt) gm = cnt - 1;
    aSrc[c] = hbuf + (size_t)(hb + gm) * FF + kk;
    bSrc[c] = w2t + ((size_t)e * HD + n0 + r) * FF + kk;
  }
  char* aDst[4];
  char* bDst[4];
#pragma unroll
  for (int c = 0; c < 4; ++c) {
    aDst[c] = Abase + (tid & 192) * 16 + c * 4096;
    bDst[c] = Bbase + (tid & 192) * 16 + c * 4096;
  }

  f32x4 acc[4][4] = {};
  const int lr = lane & 15, lk = lane >> 4;

  for (int kt = 0; kt < FF / 64; ++kt) {
#pragma unroll
    for (int c = 0; c < 4; ++c) {
      gload16(aSrc[c], aDst[c]);
      gload16(bSrc[c], bDst[c]);
      aSrc[c] += 64; bSrc[c] += 64;
    }
    asm volatile("s_waitcnt vmcnt(0)");
    __syncthreads();
#pragma unroll
    for (int k2 = 0; k2 < 2; ++k2) {
      half8 a[4], b[4];
#pragma unroll
      for (int mf = 0; mf < 4; ++mf) {
        int row = wm * 64 + mf * 16 + lr;
        int off = row * 128 + (((k2 * 64) + (lk << 4)) ^ ((row & 7) << 4));
        a[mf] = *(const half8*)(Abase + off);
      }
#pragma unroll
      for (int nf = 0; nf < 4; ++nf) {
        int row = wn * 64 + nf * 16 + lr;
        int off = row * 128 + (((k2 * 64) + (lk << 4)) ^ ((row & 7) << 4));
        b[nf] = *(const half8*)(Bbase + off);
      }
#pragma unroll
      for (int mf = 0; mf < 4; ++mf)
#pragma unroll
        for (int nf = 0; nf < 4; ++nf)
          acc[mf][nf] = __builtin_amdgcn_mfma_f32_16x16x32_f16(a[mf], b[nf], acc[mf][nf], 0, 0, 0);
    }
    __syncthreads();
  }

  // epilogue: p * (acc + b2) scattered to out[token][n] (2 commutative adds/element)
#pragma unroll
  for (int mf = 0; mf < 4; ++mf) {
    int mb = wm * 64 + mf * 16 + lk * 4;
    int tk[4]; float pw[4]; bool val[4];
#pragma unroll
    for (int j = 0; j < 4; ++j) {
      int gm = m0 + mb + j;
      val[j] = (gm < cnt);
      int idx = e * NTOK + (val[j] ? gm : 0);
      tk[j] = tokL[idx];
      pw[j] = wL[idx];
    }
#pragma unroll
    for (int nf = 0; nf < 4; ++nf) {
      int n = n0 + wn * 64 + nf * 16 + lr;
      float b2v = b2[(size_t)e * HD + n];
#pragma unroll
      for (int j = 0; j < 4; ++j) {
        if (val[j]) {
          atomicAdd(out + (size_t)tk[j] * HD + n, pw[j] * (acc[mf][nf][j] + b2v));
        }
      }
    }
  }
}

// ---------------- launch ----------------
extern "C" void kernel_launch(void* const* d_in, const int* in_sizes, int n_in,
                              void* d_out, int out_size, void* d_ws, size_t ws_size,
                              hipStream_t stream) {
  const float* x    = (const float*)d_in[0];
  const float* grad = (const float*)d_in[1];
  const float* Wr   = (const float*)d_in[2];
  const float* br   = (const float*)d_in[3];
  const float* W1   = (const float*)d_in[4];
  const float* b1   = (const float*)d_in[5];
  const float* W2   = (const float*)d_in[6];
  const float* b2   = (const float*)d_in[7];
  float* out = (float*)d_out;

  char* ws = (char*)d_ws;
  // workspace layout (bytes)
  int*      counts = (int*)(ws + 0);            // 32 B
  int*      basep  = (int*)(ws + 128);          // 32 B
  int*      tokL   = (int*)(ws + 256);          // 8*8192*4 = 256 KiB
  float*    wL     = (float*)(ws + 262400);     // 256 KiB
  _Float16* xh     = (_Float16*)(ws + 524544);      // 16 MiB
  _Float16* w1t    = (_Float16*)(ws + 17301760);    // 64 MiB
  _Float16* w2t    = (_Float16*)(ws + 84410624);    // 64 MiB
  _Float16* hbuf   = (_Float16*)(ws + 151519488);   // 128 MiB ; end = 285737216
  if (ws_size < 285737216ull) return;  // insufficient workspace -> output stays poisoned (visible failure)

  hipMemsetAsync(counts, 0, 64, stream);
  hipMemsetAsync(out, 0, (size_t)NTOK * HD * 4, stream);

  convx_k<<<(NTOK * HD / 4) / 256, 256, 0, stream>>>(x, xh);
  transc_k<<<dim3(FF / 64, HD / 64, NE), 256, 0, stream>>>(W1, w1t, HD, FF);  // [E][1024][4096] -> [E][4096][1024]
  transc_k<<<dim3(HD / 64, FF / 64, NE), 256, 0, stream>>>(W2, w2t, FF, HD);  // [E][4096][1024] -> [E][1024][4096]
  router_k<<<NTOK / 4, 256, 0, stream>>>(x, grad, Wr, br, counts, tokL, wL);
  prefix_k<<<1, 64, 0, stream>>>(counts, basep);

  gemm1_k<<<dim3(FF / 128, NTOK / 128, NE), 256, 0, stream>>>(xh, w1t, b1, tokL, counts, basep, hbuf);
  gemm2_k<<<dim3(HD / 128, NTOK / 128, NE), 256, 0, stream>>>(hbuf, w2t, b2, tokL, wL, counts, basep, out);
}

// Round 2
// 1057.006 us; speedup vs baseline: 1.1286x; 1.1286x over previous
//
#include <hip/hip_runtime.h>
#include <hip/hip_bf16.h>
#include <stdint.h>

// Sparse MoE: N=8192 tokens, H=1024, E=8 experts, top-K=2, FF=4096.
// router -> per-expert token lists -> grouped f16 MFMA GEMMs with
// 2-phase double-buffered LDS schedule (stage(k+1) overlaps compute(k)).

#define NTOK 8192
#define HD   1024
#define NE   8
#define FF   4096
#define MAXT 136   // max total m-tiles: sum(ceil(cnt_e/128)) <= 128+7

typedef float  f32x4 __attribute__((ext_vector_type(4)));
typedef _Float16 half8 __attribute__((ext_vector_type(8)));
typedef _Float16 half4 __attribute__((ext_vector_type(4)));

#define AS1 __attribute__((address_space(1)))
#define AS3 __attribute__((address_space(3)))

__device__ __forceinline__ void gload16(const void* g, void* l) {
  __builtin_amdgcn_global_load_lds((AS1 void*)g, (AS3 void*)l, 16, 0, 0);
}

// given global tile index t, find (expert, m0, cnt); false => no work
__device__ __forceinline__ bool tile_lookup(const int* __restrict__ counts,
                                            int t, int& e, int& m0, int& cnt) {
#pragma unroll
  for (int i = 0; i < NE; ++i) {
    int c = counts[i];
    int nt = (c + 127) >> 7;
    if (t < nt) { e = i; m0 = t << 7; cnt = c; return true; }
    t -= nt;
  }
  return false;
}

// ---------------- prep: convert x to f16 ----------------
__global__ __launch_bounds__(256) void convx_k(const float* __restrict__ x,
                                               _Float16* __restrict__ xh) {
  int i = blockIdx.x * 256 + threadIdx.x;
  float4 v = ((const float4*)x)[i];
  half4 h = {(_Float16)v.x, (_Float16)v.y, (_Float16)v.z, (_Float16)v.w};
  ((half4*)xh)[i] = h;
}

// ---------------- prep: convert + transpose weights ----------------
// src: [E][R][C] f32 row-major  ->  dst: [E][C][R] f16 row-major
__global__ __launch_bounds__(256) void transc_k(const float* __restrict__ src,
                                                _Float16* __restrict__ dst,
                                                int R, int C) {
  __shared__ float t[64][65];
  const int e = blockIdx.z;
  const size_t eb = (size_t)e * R * C;
  const int r0 = blockIdx.y * 64, c0 = blockIdx.x * 64;
  const int tid = threadIdx.x;
#pragma unroll
  for (int i = 0; i < 4; ++i) {
    int idx = tid + i * 256;
    int r = idx >> 4, c = (idx & 15) * 4;
    float4 v = *(const float4*)(src + eb + (size_t)(r0 + r) * C + (c0 + c));
    t[r][c] = v.x; t[r][c + 1] = v.y; t[r][c + 2] = v.z; t[r][c + 3] = v.w;
  }
  __syncthreads();
#pragma unroll
  for (int i = 0; i < 4; ++i) {
    int idx = tid + i * 256;
    int cr = idx >> 4, r4 = (idx & 15) * 4;
    half4 o = {(_Float16)t[r4][cr], (_Float16)t[r4 + 1][cr],
               (_Float16)t[r4 + 2][cr], (_Float16)t[r4 + 3][cr]};
    *(half4*)(dst + eb + (size_t)(c0 + cr) * R + (r0 + r4)) = o;
  }
}

// ---------------- router ----------------
__global__ __launch_bounds__(256) void router_k(const float* __restrict__ x,
                                                const float* __restrict__ grad,
                                                const float* __restrict__ Wr,
                                                const float* __restrict__ br,
                                                int* __restrict__ counts,
                                                int* __restrict__ tokL,
                                                float* __restrict__ wL) {
  const int lane = threadIdx.x & 63;
  const int n = blockIdx.x * 4 + (threadIdx.x >> 6);
  float acc[8] = {0.f, 0.f, 0.f, 0.f, 0.f, 0.f, 0.f, 0.f};
  const float* xr = x + (size_t)n * HD;
#pragma unroll 4
  for (int i = 0; i < 16; ++i) {
    float xv = xr[i * 64 + lane];
    const float* wr = Wr + (size_t)(i * 64 + lane) * NE;
    float4 w0 = *(const float4*)wr;
    float4 w1 = *(const float4*)(wr + 4);
    acc[0] += xv * w0.x; acc[1] += xv * w0.y; acc[2] += xv * w0.z; acc[3] += xv * w0.w;
    acc[4] += xv * w1.x; acc[5] += xv * w1.y; acc[6] += xv * w1.z; acc[7] += xv * w1.w;
  }
#pragma unroll
  for (int off = 32; off > 0; off >>= 1)
#pragma unroll
    for (int e = 0; e < 8; ++e) acc[e] += __shfl_xor(acc[e], off, 64);
  if (lane == 0) {
    float gv = grad[n];
    float lg[8];
#pragma unroll
    for (int e = 0; e < 8; ++e) lg[e] = acc[e] + gv * Wr[HD * NE + e] + br[e];
    float m = lg[0];
#pragma unroll
    for (int e = 1; e < 8; ++e) m = fmaxf(m, lg[e]);
    float s = 0.f, p[8];
#pragma unroll
    for (int e = 0; e < 8; ++e) { p[e] = expf(lg[e] - m); s += p[e]; }
    int i1 = 0;
#pragma unroll
    for (int e = 1; e < 8; ++e) if (lg[e] > lg[i1]) i1 = e;
    int i2 = (i1 == 0) ? 1 : 0;
#pragma unroll
    for (int e = 0; e < 8; ++e) if (e != i1 && lg[e] > lg[i2]) i2 = e;
    float inv = 1.0f / s;
    int p1 = atomicAdd(&counts[i1], 1);
    tokL[i1 * NTOK + p1] = n; wL[i1 * NTOK + p1] = p[i1] * inv;
    int p2 = atomicAdd(&counts[i2], 1);
    tokL[i2 * NTOK + p2] = n; wL[i2 * NTOK + p2] = p[i2] * inv;
  }
}

__global__ void prefix_k(const int* __restrict__ counts, int* __restrict__ base) {
  if (threadIdx.x == 0) {
    int s = 0;
    for (int e = 0; e < NE; ++e) { base[e] = s; s += counts[e]; }
  }
}

// ---------------- GEMM1: h = gelu(Xg @ W1 + b1) ----------------
// 128x128 tile, BK=64, double-buffered LDS (2x32KB), 2-phase schedule.
__global__ __launch_bounds__(256) void gemm1_k(const _Float16* __restrict__ xh,
                                               const _Float16* __restrict__ w1t,
                                               const float* __restrict__ b1,
                                               const int* __restrict__ tokL,
                                               const int* __restrict__ counts,
                                               const int* __restrict__ base,
                                               _Float16* __restrict__ hbuf) {
  int e, m0, cnt;
  if (!tile_lookup(counts, blockIdx.y, e, m0, cnt)) return;
  const int n0 = blockIdx.x * 128;
  const int hb = base[e];

  __shared__ __align__(16) char smem[65536];  // [A0|B0|A1|B1] 16KB each

  const int tid = threadIdx.x;
  const int lane = tid & 63;
  const int wid = tid >> 6;
  const int wm = wid >> 1, wn = wid & 1;
  const int lr = lane & 15, lk = lane >> 4;

  // staging: thread covers rows srow+32c at swizzled k-chunk kk
  const int srow = tid >> 3;
  const int kk = ((tid & 7) ^ (srow & 7)) << 3;
  const _Float16* aSrc[4];
  const _Float16* bSrc[4];
#pragma unroll
  for (int c = 0; c < 4; ++c) {
    int r = srow + 32 * c;
    int gm = m0 + r; if (gm >= cnt) gm = cnt - 1;
    int t = tokL[e * NTOK + gm];
    aSrc[c] = xh + (size_t)t * HD + kk;
    bSrc[c] = w1t + ((size_t)e * FF + n0 + r) * HD + kk;
  }
  const int ldsOff = (tid & 192) * 16;  // wave-uniform; HW adds lane*16

  f32x4 acc[4][4] = {};

  auto stage = [&](int p) {
    char* A = smem + p * 32768 + ldsOff;
    char* B = smem + p * 32768 + 16384 + ldsOff;
#pragma unroll
    for (int c = 0; c < 4; ++c) {
      gload16(aSrc[c], A + c * 4096);
      gload16(bSrc[c], B + c * 4096);
      aSrc[c] += 64; bSrc[c] += 64;
    }
  };
  auto compute = [&](int p) {
    const char* A = smem + p * 32768;
    const char* B = A + 16384;
#pragma unroll
    for (int k2 = 0; k2 < 2; ++k2) {
      half8 a[4], b[4];
#pragma unroll
      for (int mf = 0; mf < 4; ++mf) {
        int row = wm * 64 + mf * 16 + lr;
        int off = row * 128 + (((k2 * 64) + (lk << 4)) ^ ((row & 7) << 4));
        a[mf] = *(const half8*)(A + off);
      }
#pragma unroll
      for (int nf = 0; nf < 4; ++nf) {
        int row = wn * 64 + nf * 16 + lr;
        int off = row * 128 + (((k2 * 64) + (lk << 4)) ^ ((row & 7) << 4));
        b[nf] = *(const half8*)(B + off);
      }
#pragma unroll
      for (int mf = 0; mf < 4; ++mf)
#pragma unroll
        for (int nf = 0; nf < 4; ++nf)
          acc[mf][nf] = __builtin_amdgcn_mfma_f32_16x16x32_f16(a[mf], b[nf], acc[mf][nf], 0, 0, 0);
    }
  };

  stage(0);
  asm volatile("s_waitcnt vmcnt(0)" ::: "memory");
  __builtin_amdgcn_s_barrier();
  const int NK = HD / 64;
  for (int kt = 0; kt < NK - 1; ++kt) {
    int p = kt & 1;
    stage(p ^ 1);          // prefetch next K-tile (in flight during compute)
    compute(p);
    asm volatile("s_waitcnt lgkmcnt(0)" ::: "memory");
    asm volatile("s_waitcnt vmcnt(0)" ::: "memory");
    __builtin_amdgcn_s_barrier();
  }
  compute((NK - 1) & 1);
  asm volatile("s_waitcnt lgkmcnt(0)" ::: "memory");
  __builtin_amdgcn_s_barrier();

  // epilogue: bias + exact-erf GELU -> LDS bounce -> coalesced half8 stores
#define OSTR 132  // f16 elements per row (264B: 4-row stride = 1056B ≡ 32B mod 128 -> conflict-spread)
  _Float16* ot = (_Float16*)smem;
#pragma unroll
  for (int nf = 0; nf < 4; ++nf) {
    int col = wn * 64 + nf * 16 + lr;
    float bias = b1[(size_t)e * FF + n0 + col];
#pragma unroll
    for (int mf = 0; mf < 4; ++mf) {
      int rb = wm * 64 + mf * 16 + lk * 4;
#pragma unroll
      for (int j = 0; j < 4; ++j) {
        float v = acc[mf][nf][j] + bias;
        v = 0.5f * v * (1.0f + erff(v * 0.70710678118654752f));
        ot[(rb + j) * OSTR + col] = (_Float16)v;
      }
    }
  }
  asm volatile("s_waitcnt lgkmcnt(0)" ::: "memory");
  __builtin_amdgcn_s_barrier();
#pragma unroll
  for (int i = 0; i < 8; ++i) {
    int row = i * 16 + (tid >> 4);
    int gm = m0 + row;
    half8 v = *(const half8*)(ot + row * OSTR + (tid & 15) * 8);
    if (gm < cnt)
      *(half8*)(hbuf + (size_t)(hb + gm) * FF + n0 + (tid & 15) * 8) = v;
  }
#undef OSTR
}

// ---------------- GEMM2: out += p * (h @ W2 + b2), atomic scatter ----------------
__global__ __launch_bounds__(256) void gemm2_k(const _Float16* __restrict__ hbuf,
                                               const _Float16* __restrict__ w2t,
                                               const float* __restrict__ b2,
                                               const int* __restrict__ tokL,
                                               const float* __restrict__ wL,
                                               const int* __restrict__ counts,
                                               const int* __restrict__ base,
                                               float* __restrict__ out) {
  int e, m0, cnt;
  if (!tile_lookup(counts, blockIdx.y, e, m0, cnt)) return;
  const int n0 = blockIdx.x * 128;
  const int hb = base[e];

  __shared__ __align__(16) char smem[65536];

  const int tid = threadIdx.x;
  const int lane = tid & 63;
  const int wid = tid >> 6;
  const int wm = wid >> 1, wn = wid & 1;
  const int lr = lane & 15, lk = lane >> 4;

  const int srow = tid >> 3;
  const int kk = ((tid & 7) ^ (srow & 7)) << 3;
  const _Float16* aSrc[4];
  const _Float16* bSrc[4];
#pragma unroll
  for (int c = 0; c < 4; ++c) {
    int r = srow + 32 * c;
    int gm = m0 + r; if (gm >= cnt) gm = cnt - 1;
    aSrc[c] = hbuf + (size_t)(hb + gm) * FF + kk;
    bSrc[c] = w2t + ((size_t)e * HD + n0 + r) * FF + kk;
  }
  const int ldsOff = (tid & 192) * 16;

  f32x4 acc[4][4] = {};

  auto stage = [&](int p) {
    char* A = smem + p * 32768 + ldsOff;
    char* B = smem + p * 32768 + 16384 + ldsOff;
#pragma unroll
    for (int c = 0; c < 4; ++c) {
      gload16(aSrc[c], A + c * 4096);
      gload16(bSrc[c], B + c * 4096);
      aSrc[c] += 64; bSrc[c] += 64;
    }
  };
  auto compute = [&](int p) {
    const char* A = smem + p * 32768;
    const char* B = A + 16384;
#pragma unroll
    for (int k2 = 0; k2 < 2; ++k2) {
      half8 a[4], b[4];
#pragma unroll
      for (int mf = 0; mf < 4; ++mf) {
        int row = wm * 64 + mf * 16 + lr;
        int off = row * 128 + (((k2 * 64) + (lk << 4)) ^ ((row & 7) << 4));
        a[mf] = *(const half8*)(A + off);
      }
#pragma unroll
      for (int nf = 0; nf < 4; ++nf) {
        int row = wn * 64 + nf * 16 + lr;
        int off = row * 128 + (((k2 * 64) + (lk << 4)) ^ ((row & 7) << 4));
        b[nf] = *(const half8*)(B + off);
      }
#pragma unroll
      for (int mf = 0; mf < 4; ++mf)
#pragma unroll
        for (int nf = 0; nf < 4; ++nf)
          acc[mf][nf] = __builtin_amdgcn_mfma_f32_16x16x32_f16(a[mf], b[nf], acc[mf][nf], 0, 0, 0);
    }
  };

  stage(0);
  asm volatile("s_waitcnt vmcnt(0)" ::: "memory");
  __builtin_amdgcn_s_barrier();
  const int NK = FF / 64;
  for (int kt = 0; kt < NK - 1; ++kt) {
    int p = kt & 1;
    stage(p ^ 1);
    compute(p);
    asm volatile("s_waitcnt lgkmcnt(0)" ::: "memory");
    asm volatile("s_waitcnt vmcnt(0)" ::: "memory");
    __builtin_amdgcn_s_barrier();
  }
  compute((NK - 1) & 1);

  // epilogue: p * (acc + b2) scattered to out[token][n]
#pragma unroll
  for (int mf = 0; mf < 4; ++mf) {
    int mb = wm * 64 + mf * 16 + lk * 4;
    int tk[4]; float pw[4]; bool val[4];
#pragma unroll
    for (int j = 0; j < 4; ++j) {
      int gm = m0 + mb + j;
      val[j] = (gm < cnt);
      int idx = e * NTOK + (val[j] ? gm : 0);
      tk[j] = tokL[idx];
      pw[j] = wL[idx];
    }
#pragma unroll
    for (int nf = 0; nf < 4; ++nf) {
      int n = n0 + wn * 64 + nf * 16 + lr;
      float b2v = b2[(size_t)e * HD + n];
#pragma unroll
      for (int j = 0; j < 4; ++j) {
        if (val[j]) {
          atomicAdd(out + (size_t)tk[j] * HD + n, pw[j] * (acc[mf][nf][j] + b2v));
        }
      }
    }
  }
}

// ---------------- launch ----------------
extern "C" void kernel_launch(void* const* d_in, const int* in_sizes, int n_in,
                              void* d_out, int out_size, void* d_ws, size_t ws_size,
                              hipStream_t stream) {
  const float* x    = (const float*)d_in[0];
  const float* grad = (const float*)d_in[1];
  const float* Wr   = (const float*)d_in[2];
  const float* br   = (const float*)d_in[3];
  const float* W1   = (const float*)d_in[4];
  const float* b1   = (const float*)d_in[5];
  const float* W2   = (const float*)d_in[6];
  const float* b2   = (const float*)d_in[7];
  float* out = (float*)d_out;

  char* ws = (char*)d_ws;
  int*      counts = (int*)(ws + 0);
  int*      basep  = (int*)(ws + 128);
  int*      tokL   = (int*)(ws + 256);
  float*    wL     = (float*)(ws + 262400);
  _Float16* xh     = (_Float16*)(ws + 524544);
  _Float16* w1t    = (_Float16*)(ws + 17301760);
  _Float16* w2t    = (_Float16*)(ws + 84410624);
  _Float16* hbuf   = (_Float16*)(ws + 151519488);   // end = 285737216
  if (ws_size < 285737216ull) return;

  hipMemsetAsync(counts, 0, 64, stream);
  hipMemsetAsync(out, 0, (size_t)NTOK * HD * 4, stream);

  convx_k<<<(NTOK * HD / 4) / 256, 256, 0, stream>>>(x, xh);
  transc_k<<<dim3(FF / 64, HD / 64, NE), 256, 0, stream>>>(W1, w1t, HD, FF);
  transc_k<<<dim3(HD / 64, FF / 64, NE), 256, 0, stream>>>(W2, w2t, FF, HD);
  router_k<<<NTOK / 4, 256, 0, stream>>>(x, grad, Wr, br, counts, tokL, wL);
  prefix_k<<<1, 64, 0, stream>>>(counts, basep);

  gemm1_k<<<dim3(FF / 128, MAXT), 256, 0, stream>>>(xh, w1t, b1, tokL, counts, basep, hbuf);
  gemm2_k<<<dim3(HD / 128, MAXT), 256, 0, stream>>>(hbuf, w2t, b2, tokL, wL, counts, basep, out);
}

// Round 3
// 1054.877 us; speedup vs baseline: 1.1308x; 1.0020x over previous
//
#include <hip/hip_runtime.h>
#include <hip/hip_bf16.h>
#include <stdint.h>

// Sparse MoE: N=8192 tokens, H=1024, E=8 experts, top-K=2, FF=4096.
// router -> per-expert token lists -> grouped f16 MFMA GEMMs with the
// 256x256 / 8-wave / BK=64 / 8-phase counted-vmcnt schedule (T2+T3+T4+T5).

#define NTOK 8192
#define HD   1024
#define NE   8
#define FF   4096
#define MAXT 72    // max total 256-row m-tiles: sum(ceil(cnt_e/256)) <= 64+8

typedef float  f32x4 __attribute__((ext_vector_type(4)));
typedef _Float16 half8 __attribute__((ext_vector_type(8)));
typedef _Float16 half4 __attribute__((ext_vector_type(4)));

#define AS1 __attribute__((address_space(1)))
#define AS3 __attribute__((address_space(3)))

__device__ __forceinline__ void gload16(const void* g, void* l) {
  __builtin_amdgcn_global_load_lds((AS1 void*)g, (AS3 void*)l, 16, 0, 0);
}

// global 256-row tile index -> (expert, m0, cnt)
__device__ __forceinline__ bool tile_lookup(const int* __restrict__ counts,
                                            int t, int& e, int& m0, int& cnt) {
#pragma unroll
  for (int i = 0; i < NE; ++i) {
    int c = counts[i];
    int nt = (c + 255) >> 8;
    if (t < nt) { e = i; m0 = t << 8; cnt = c; return true; }
    t -= nt;
  }
  return false;
}

// ---------------- prep: convert + transpose weights ----------------
// src: [E][R][C] f32 row-major  ->  dst: [E][C][R] f16 row-major
__global__ __launch_bounds__(256) void transc_k(const float* __restrict__ src,
                                                _Float16* __restrict__ dst,
                                                int R, int C) {
  __shared__ float t[64][65];
  const int e = blockIdx.z;
  const size_t eb = (size_t)e * R * C;
  const int r0 = blockIdx.y * 64, c0 = blockIdx.x * 64;
  const int tid = threadIdx.x;
#pragma unroll
  for (int i = 0; i < 4; ++i) {
    int idx = tid + i * 256;
    int r = idx >> 4, c = (idx & 15) * 4;
    float4 v = *(const float4*)(src + eb + (size_t)(r0 + r) * C + (c0 + c));
    t[r][c] = v.x; t[r][c + 1] = v.y; t[r][c + 2] = v.z; t[r][c + 3] = v.w;
  }
  __syncthreads();
#pragma unroll
  for (int i = 0; i < 4; ++i) {
    int idx = tid + i * 256;
    int cr = idx >> 4, r4 = (idx & 15) * 4;
    half4 o = {(_Float16)t[r4][cr], (_Float16)t[r4 + 1][cr],
               (_Float16)t[r4 + 2][cr], (_Float16)t[r4 + 3][cr]};
    *(half4*)(dst + eb + (size_t)(c0 + cr) * R + (r0 + r4)) = o;
  }
}

// ---------------- router (+ fused x -> f16 conversion) ----------------
__global__ __launch_bounds__(256) void router_k(const float* __restrict__ x,
                                                const float* __restrict__ grad,
                                                const float* __restrict__ Wr,
                                                const float* __restrict__ br,
                                                int* __restrict__ counts,
                                                int* __restrict__ tokL,
                                                float* __restrict__ wL,
                                                _Float16* __restrict__ xh) {
  const int lane = threadIdx.x & 63;
  const int n = blockIdx.x * 4 + (threadIdx.x >> 6);
  float acc[8] = {0.f, 0.f, 0.f, 0.f, 0.f, 0.f, 0.f, 0.f};
  const float* xr = x + (size_t)n * HD;
  _Float16* xo = xh + (size_t)n * HD;
#pragma unroll 4
  for (int i = 0; i < 16; ++i) {
    float xv = xr[i * 64 + lane];
    xo[i * 64 + lane] = (_Float16)xv;            // fused convx
    const float* wr = Wr + (size_t)(i * 64 + lane) * NE;
    float4 w0 = *(const float4*)wr;
    float4 w1 = *(const float4*)(wr + 4);
    acc[0] += xv * w0.x; acc[1] += xv * w0.y; acc[2] += xv * w0.z; acc[3] += xv * w0.w;
    acc[4] += xv * w1.x; acc[5] += xv * w1.y; acc[6] += xv * w1.z; acc[7] += xv * w1.w;
  }
#pragma unroll
  for (int off = 32; off > 0; off >>= 1)
#pragma unroll
    for (int e = 0; e < 8; ++e) acc[e] += __shfl_xor(acc[e], off, 64);
  if (lane == 0) {
    float gv = grad[n];
    float lg[8];
#pragma unroll
    for (int e = 0; e < 8; ++e) lg[e] = acc[e] + gv * Wr[HD * NE + e] + br[e];
    float m = lg[0];
#pragma unroll
    for (int e = 1; e < 8; ++e) m = fmaxf(m, lg[e]);
    float s = 0.f, p[8];
#pragma unroll
    for (int e = 0; e < 8; ++e) { p[e] = expf(lg[e] - m); s += p[e]; }
    int i1 = 0;
#pragma unroll
    for (int e = 1; e < 8; ++e) if (lg[e] > lg[i1]) i1 = e;
    int i2 = (i1 == 0) ? 1 : 0;
#pragma unroll
    for (int e = 0; e < 8; ++e) if (e != i1 && lg[e] > lg[i2]) i2 = e;
    float inv = 1.0f / s;
    int p1 = atomicAdd(&counts[i1], 1);
    tokL[i1 * NTOK + p1] = n; wL[i1 * NTOK + p1] = p[i1] * inv;
    int p2 = atomicAdd(&counts[i2], 1);
    tokL[i2 * NTOK + p2] = n; wL[i2 * NTOK + p2] = p[i2] * inv;
  }
}

__global__ void prefix_k(const int* __restrict__ counts, int* __restrict__ base) {
  if (threadIdx.x == 0) {
    int s = 0;
    for (int e = 0; e < NE; ++e) { base[e] = s; s += counts[e]; }
  }
}

// ======== shared 8-phase machinery (macros; all indices compile-time) ========
// LDS buffer p (p in {0,1}) at p*65536: [A-half0|A-half1|B-half0|B-half1], 16KB each.
// Phase (MH,NH): every wave reads ONLY A-half MH, B-half NH (interleaved wave tiling:
// wave rows = MH*128 + wm*64 + mf*16 + lr; wave cols = NH*128 + wn*32 + nf*16 + lr).

#define DSA(BUF, MH)                                                          \
  {                                                                           \
    const char* _ab = smem + (BUF)*65536 + (MH)*16384;                        \
    _Pragma("unroll") for (int mf = 0; mf < 4; ++mf) {                        \
      int row = wm * 64 + mf * 16 + lr;                                       \
      _Pragma("unroll") for (int k2 = 0; k2 < 2; ++k2) {                      \
        int off = row * 128 + ((k2 * 64 + (lk << 4)) ^ ((row & 7) << 4));     \
        af[mf][k2] = *(const half8*)(_ab + off);                              \
      }                                                                       \
    }                                                                         \
  }

#define DSB(BUF, NH)                                                          \
  {                                                                           \
    const char* _bb = smem + (BUF)*65536 + 32768 + (NH)*16384;                \
    _Pragma("unroll") for (int nf = 0; nf < 2; ++nf) {                        \
      int row = wn * 32 + nf * 16 + lr;                                       \
      _Pragma("unroll") for (int k2 = 0; k2 < 2; ++k2) {                      \
        int off = row * 128 + ((k2 * 64 + (lk << 4)) ^ ((row & 7) << 4));     \
        bf[nf][k2] = *(const half8*)(_bb + off);                              \
      }                                                                       \
    }                                                                         \
  }

#define MFMAQ(MH, NH)                                                         \
  __builtin_amdgcn_s_setprio(1);                                              \
  _Pragma("unroll") for (int mf = 0; mf < 4; ++mf)                            \
  _Pragma("unroll") for (int nf = 0; nf < 2; ++nf)                            \
  _Pragma("unroll") for (int k2 = 0; k2 < 2; ++k2)                            \
    acc[(MH)*4 + mf][(NH)*2 + nf] = __builtin_amdgcn_mfma_f32_16x16x32_f16(   \
        af[mf][k2], bf[nf][k2], acc[(MH)*4 + mf][(NH)*2 + nf], 0, 0, 0);      \
  __builtin_amdgcn_s_setprio(0);

#define PH(BUF, MH, NH, STG, VM)                                              \
  do {                                                                        \
    DSA(BUF, MH); DSB(BUF, NH);                                               \
    STG;                                                                      \
    if (VM) asm volatile("s_waitcnt vmcnt(4)" ::: "memory");                  \
    __builtin_amdgcn_s_barrier();                                             \
    asm volatile("s_waitcnt lgkmcnt(0)" ::: "memory");                        \
    MFMAQ(MH, NH);                                                            \
    __builtin_amdgcn_s_barrier();                                             \
  } while (0)

// stage one half-tile (128 rows x 64 k f16 = 16KB) = 2 gload16 per thread
#define STAGE_A(BUF, H, KIDX)                                                 \
  {                                                                           \
    char* _d = smem + (BUF)*65536 + (H)*16384 + (wid << 10);                  \
    gload16(aP[(H)*2 + 0] + (KIDX)*64, _d);                                   \
    gload16(aP[(H)*2 + 1] + (KIDX)*64, _d + 8192);                            \
  }
#define STAGE_B(BUF, H, KIDX, LDB)                                            \
  {                                                                           \
    char* _d = smem + (BUF)*65536 + 32768 + (H)*16384 + (wid << 10);          \
    gload16(bP + (size_t)((H)*128) * (LDB) + (KIDX)*64, _d);                  \
    gload16(bP + (size_t)((H)*128 + 64) * (LDB) + (KIDX)*64, _d + 8192);      \
  }

// ---------------- GEMM1: h = gelu(Xg @ W1 + b1) ----------------
__global__ __launch_bounds__(512, 2) void gemm1_k(const _Float16* __restrict__ xh,
                                                  const _Float16* __restrict__ w1t,
                                                  const float* __restrict__ b1,
                                                  const int* __restrict__ tokL,
                                                  const int* __restrict__ counts,
                                                  const int* __restrict__ base,
                                                  _Float16* __restrict__ hbuf) {
  int e, m0, cnt;
  if (!tile_lookup(counts, blockIdx.y, e, m0, cnt)) return;
  const int n0 = blockIdx.x * 256;
  const int hb = base[e];

  __shared__ __align__(16) char smem[131072];

  const int tid = threadIdx.x;
  const int lane = tid & 63;
  const int wid = tid >> 6;
  const int wm = wid & 1, wn = wid >> 1;
  const int lr = lane & 15, lk = lane >> 4;

  // staging: thread covers LDS row srow (per 64-row chunk) at swizzled k-chunk kk
  const int srow = tid >> 3;                       // 0..63
  const int kk = ((tid & 7) ^ (srow & 7)) << 3;    // f16 elements
  const _Float16* aP[4];
#pragma unroll
  for (int h = 0; h < 2; ++h)
#pragma unroll
    for (int j = 0; j < 2; ++j) {
      int r = h * 128 + j * 64 + srow;
      int gm = m0 + r; if (gm >= cnt) gm = cnt - 1;
      aP[h * 2 + j] = xh + (size_t)tokL[e * NTOK + gm] * HD + kk;
    }
  const _Float16* bP = w1t + ((size_t)e * FF + n0 + srow) * HD + kk;

  f32x4 acc[8][4] = {};
  half8 af[4][2], bf[2][2];

  // prologue: full tile0 -> L0; A-half0,B-half1 of tile1 -> L1
  STAGE_A(0, 0, 0); STAGE_A(0, 1, 0); STAGE_B(0, 0, 0, HD); STAGE_B(0, 1, 0, HD);
  STAGE_A(1, 0, 1); STAGE_B(1, 1, 1, HD);
  asm volatile("s_waitcnt vmcnt(4)" ::: "memory");
  __builtin_amdgcn_s_barrier();

  const int NK = HD / 64;          // 16 K-tiles
  for (int it = 0; it < NK / 2; ++it) {
    int t1 = 2 * it + 1;
    int t0n = 2 * it + 2; if (t0n > NK - 1) t0n = NK - 1;
    int t1n = 2 * it + 3; if (t1n > NK - 1) t1n = NK - 1;
    PH(0, 0, 0, STAGE_A(1, 1, t1), 0);
    PH(0, 0, 1, STAGE_B(1, 0, t1, HD), 0);
    PH(0, 1, 1, STAGE_A(0, 0, t0n), 0);
    PH(0, 1, 0, STAGE_B(0, 1, t0n, HD), 1);
    PH(1, 0, 0, STAGE_A(0, 1, t0n), 0);
    PH(1, 0, 1, STAGE_B(0, 0, t0n, HD), 0);
    PH(1, 1, 1, STAGE_A(1, 0, t1n), 0);
    PH(1, 1, 0, STAGE_B(1, 1, t1n, HD), 1);
  }
  asm volatile("s_waitcnt vmcnt(0) lgkmcnt(0)" ::: "memory");
  __builtin_amdgcn_s_barrier();

  // epilogue: bias + exact-erf GELU -> swizzled LDS bounce -> coalesced half8 stores
#pragma unroll
  for (int ni = 0; ni < 4; ++ni) {
    const int nh = ni >> 1, nf = ni & 1;
    int col = nh * 128 + wn * 32 + nf * 16 + lr;
    float bias = b1[(size_t)e * FF + n0 + col];
#pragma unroll
    for (int mi = 0; mi < 8; ++mi) {
      const int mh = mi >> 2, mf = mi & 3;
      int rb = mh * 128 + wm * 64 + mf * 16 + lk * 4;
#pragma unroll
      for (int j = 0; j < 4; ++j) {
        float v = acc[mi][ni][j] + bias;
        v = 0.5f * v * (1.0f + erff(v * 0.70710678118654752f));
        int row = rb + j;
        *(_Float16*)(smem + row * 512 + ((col * 2) ^ ((row & 7) << 4))) = (_Float16)v;
      }
    }
  }
  asm volatile("s_waitcnt lgkmcnt(0)" ::: "memory");
  __builtin_amdgcn_s_barrier();
#pragma unroll
  for (int ps = 0; ps < 16; ++ps) {
    int row = ps * 16 + (tid >> 5);
    int c = tid & 31;
    int lc = c ^ (row & 7);
    half8 v = *(const half8*)(smem + row * 512 + c * 16);
    int gm = m0 + row;
    if (gm < cnt)
      *(half8*)(hbuf + (size_t)(hb + gm) * FF + n0 + lc * 8) = v;
  }
}

// ---------------- GEMM2: out += p * (h @ W2 + b2), K-split x2, atomic scatter ----------------
__global__ __launch_bounds__(512, 2) void gemm2_k(const _Float16* __restrict__ hbuf,
                                                  const _Float16* __restrict__ w2t,
                                                  const float* __restrict__ b2,
                                                  const int* __restrict__ tokL,
                                                  const float* __restrict__ wL,
                                                  const int* __restrict__ counts,
                                                  const int* __restrict__ base,
                                                  float* __restrict__ out) {
  int e, m0, cnt;
  if (!tile_lookup(counts, blockIdx.y, e, m0, cnt)) return;
  const int n0 = blockIdx.x * 256;
  const int ks = blockIdx.z;             // K-split half: k in [ks*2048, ks*2048+2048)
  const int hb = base[e];

  __shared__ __align__(16) char smem[131072];

  const int tid = threadIdx.x;
  const int lane = tid & 63;
  const int wid = tid >> 6;
  const int wm = wid & 1, wn = wid >> 1;
  const int lr = lane & 15, lk = lane >> 4;

  const int srow = tid >> 3;
  const int kk = ((tid & 7) ^ (srow & 7)) << 3;
  const size_t kbase = (size_t)ks * 2048;
  const _Float16* aP[4];
#pragma unroll
  for (int h = 0; h < 2; ++h)
#pragma unroll
    for (int j = 0; j < 2; ++j) {
      int r = h * 128 + j * 64 + srow;
      int gm = m0 + r; if (gm >= cnt) gm = cnt - 1;
      aP[h * 2 + j] = hbuf + (size_t)(hb + gm) * FF + kbase + kk;
    }
  const _Float16* bP = w2t + ((size_t)e * HD + n0 + srow) * FF + kbase + kk;

  f32x4 acc[8][4] = {};
  half8 af[4][2], bf[2][2];

  STAGE_A(0, 0, 0); STAGE_A(0, 1, 0); STAGE_B(0, 0, 0, FF); STAGE_B(0, 1, 0, FF);
  STAGE_A(1, 0, 1); STAGE_B(1, 1, 1, FF);
  asm volatile("s_waitcnt vmcnt(4)" ::: "memory");
  __builtin_amdgcn_s_barrier();

  const int NK = 2048 / 64;        // 32 K-tiles per split half
  for (int it = 0; it < NK / 2; ++it) {
    int t1 = 2 * it + 1;
    int t0n = 2 * it + 2; if (t0n > NK - 1) t0n = NK - 1;
    int t1n = 2 * it + 3; if (t1n > NK - 1) t1n = NK - 1;
    PH(0, 0, 0, STAGE_A(1, 1, t1), 0);
    PH(0, 0, 1, STAGE_B(1, 0, t1, FF), 0);
    PH(0, 1, 1, STAGE_A(0, 0, t0n), 0);
    PH(0, 1, 0, STAGE_B(0, 1, t0n, FF), 1);
    PH(1, 0, 0, STAGE_A(0, 1, t0n), 0);
    PH(1, 0, 1, STAGE_B(0, 0, t0n, FF), 0);
    PH(1, 1, 1, STAGE_A(1, 0, t1n), 0);
    PH(1, 1, 0, STAGE_B(1, 1, t1n, FF), 1);
  }
  asm volatile("s_waitcnt vmcnt(0) lgkmcnt(0)" ::: "memory");
  __builtin_amdgcn_s_barrier();

  // epilogue: p * (acc [+ b2 if ks==0]) atomically scattered to out[token][n]
  float b2v[4];
#pragma unroll
  for (int ni = 0; ni < 4; ++ni) {
    const int nh = ni >> 1, nf = ni & 1;
    int n = n0 + nh * 128 + wn * 32 + nf * 16 + lr;
    b2v[ni] = (ks == 0) ? b2[(size_t)e * HD + n] : 0.0f;
  }
#pragma unroll
  for (int mi = 0; mi < 8; ++mi) {
    const int mh = mi >> 2, mf = mi & 3;
    int rb = m0 + mh * 128 + wm * 64 + mf * 16 + lk * 4;
    int tk[4]; float pw[4]; bool ok[4];
#pragma unroll
    for (int j = 0; j < 4; ++j) {
      int gm = rb + j;
      ok[j] = (gm < cnt);
      int idx = e * NTOK + (ok[j] ? gm : 0);
      tk[j] = tokL[idx];
      pw[j] = wL[idx];
    }
#pragma unroll
    for (int ni = 0; ni < 4; ++ni) {
      const int nh = ni >> 1, nf = ni & 1;
      int n = n0 + nh * 128 + wn * 32 + nf * 16 + lr;
#pragma unroll
      for (int j = 0; j < 4; ++j) {
        if (ok[j])
          atomicAdd(out + (size_t)tk[j] * HD + n, pw[j] * (acc[mi][ni][j] + b2v[ni]));
      }
    }
  }
}

// ---------------- launch ----------------
extern "C" void kernel_launch(void* const* d_in, const int* in_sizes, int n_in,
                              void* d_out, int out_size, void* d_ws, size_t ws_size,
                              hipStream_t stream) {
  const float* x    = (const float*)d_in[0];
  const float* grad = (const float*)d_in[1];
  const float* Wr   = (const float*)d_in[2];
  const float* br   = (const float*)d_in[3];
  const float* W1   = (const float*)d_in[4];
  const float* b1   = (const float*)d_in[5];
  const float* W2   = (const float*)d_in[6];
  const float* b2   = (const float*)d_in[7];
  float* out = (float*)d_out;

  char* ws = (char*)d_ws;
  int*      counts = (int*)(ws + 0);
  int*      basep  = (int*)(ws + 128);
  int*      tokL   = (int*)(ws + 256);
  float*    wL     = (float*)(ws + 262400);
  _Float16* xh     = (_Float16*)(ws + 524544);
  _Float16* w1t    = (_Float16*)(ws + 17301760);
  _Float16* w2t    = (_Float16*)(ws + 84410624);
  _Float16* hbuf   = (_Float16*)(ws + 151519488);   // end = 285737216
  if (ws_size < 285737216ull) return;

  hipMemsetAsync(counts, 0, 64, stream);
  hipMemsetAsync(out, 0, (size_t)NTOK * HD * 4, stream);

  transc_k<<<dim3(FF / 64, HD / 64, NE), 256, 0, stream>>>(W1, w1t, HD, FF);
  transc_k<<<dim3(HD / 64, FF / 64, NE), 256, 0, stream>>>(W2, w2t, FF, HD);
  router_k<<<NTOK / 4, 256, 0, stream>>>(x, grad, Wr, br, counts, tokL, wL, xh);
  prefix_k<<<1, 64, 0, stream>>>(counts, basep);

  gemm1_k<<<dim3(FF / 256, MAXT), 512, 0, stream>>>(xh, w1t, b1, tokL, counts, basep, hbuf);
  gemm2_k<<<dim3(HD / 256, MAXT, 2), 512, 0, stream>>>(hbuf, w2t, b2, tokL, wL, counts, basep, out);
}

// Round 5
// 1021.734 us; speedup vs baseline: 1.1675x; 1.0324x over previous
//
#include <hip/hip_runtime.h>
#include <hip/hip_bf16.h>
#include <stdint.h>

// Sparse MoE: N=8192 tokens, H=1024, E=8 experts, top-K=2, FF=4096.
// router -> per-expert token lists -> grouped f16 MFMA GEMMs with the
// 256x256 / 8-wave / BK=64 / 8-phase counted-vmcnt schedule, Gray-code
// operand reuse (load only the changed A/B half per phase; 48 b128/iter).

#define NTOK 8192
#define HD   1024
#define NE   8
#define FF   4096
#define MAXT 72    // max total 256-row m-tiles: sum(ceil(cnt_e/256)) <= 64+8

typedef float  f32x4 __attribute__((ext_vector_type(4)));
typedef _Float16 half8 __attribute__((ext_vector_type(8)));
typedef _Float16 half4 __attribute__((ext_vector_type(4)));

#define AS1 __attribute__((address_space(1)))
#define AS3 __attribute__((address_space(3)))

__device__ __forceinline__ void gload16(const void* g, void* l) {
  __builtin_amdgcn_global_load_lds((AS1 void*)g, (AS3 void*)l, 16, 0, 0);
}

// global 256-row tile index -> (expert, m0, cnt)
__device__ __forceinline__ bool tile_lookup(const int* __restrict__ counts,
                                            int t, int& e, int& m0, int& cnt) {
#pragma unroll
  for (int i = 0; i < NE; ++i) {
    int c = counts[i];
    int nt = (c + 255) >> 8;
    if (t < nt) { e = i; m0 = t << 8; cnt = c; return true; }
    t -= nt;
  }
  return false;
}

// ---------------- prep: convert + transpose weights ----------------
// src: [E][R][C] f32 row-major  ->  dst: [E][C][R] f16 row-major
__global__ __launch_bounds__(256) void transc_k(const float* __restrict__ src,
                                                _Float16* __restrict__ dst,
                                                int R, int C) {
  __shared__ float t[64][65];
  const int e = blockIdx.z;
  const size_t eb = (size_t)e * R * C;
  const int r0 = blockIdx.y * 64, c0 = blockIdx.x * 64;
  const int tid = threadIdx.x;
#pragma unroll
  for (int i = 0; i < 4; ++i) {
    int idx = tid + i * 256;
    int r = idx >> 4, c = (idx & 15) * 4;
    float4 v = *(const float4*)(src + eb + (size_t)(r0 + r) * C + (c0 + c));
    t[r][c] = v.x; t[r][c + 1] = v.y; t[r][c + 2] = v.z; t[r][c + 3] = v.w;
  }
  __syncthreads();
#pragma unroll
  for (int i = 0; i < 4; ++i) {
    int idx = tid + i * 256;
    int cr = idx >> 4, r4 = (idx & 15) * 4;
    half4 o = {(_Float16)t[r4][cr], (_Float16)t[r4 + 1][cr],
               (_Float16)t[r4 + 2][cr], (_Float16)t[r4 + 3][cr]};
    *(half4*)(dst + eb + (size_t)(c0 + cr) * R + (r0 + r4)) = o;
  }
}

// ---------------- router (+ fused x -> f16 conversion) ----------------
__global__ __launch_bounds__(256) void router_k(const float* __restrict__ x,
                                                const float* __restrict__ grad,
                                                const float* __restrict__ Wr,
                                                const float* __restrict__ br,
                                                int* __restrict__ counts,
                                                int* __restrict__ tokL,
                                                float* __restrict__ wL,
                                                _Float16* __restrict__ xh) {
  const int lane = threadIdx.x & 63;
  const int n = blockIdx.x * 4 + (threadIdx.x >> 6);
  float acc[8] = {0.f, 0.f, 0.f, 0.f, 0.f, 0.f, 0.f, 0.f};
  const float* xr = x + (size_t)n * HD;
  _Float16* xo = xh + (size_t)n * HD;
#pragma unroll 4
  for (int i = 0; i < 16; ++i) {
    float xv = xr[i * 64 + lane];
    xo[i * 64 + lane] = (_Float16)xv;            // fused convx
    const float* wr = Wr + (size_t)(i * 64 + lane) * NE;
    float4 w0 = *(const float4*)wr;
    float4 w1 = *(const float4*)(wr + 4);
    acc[0] += xv * w0.x; acc[1] += xv * w0.y; acc[2] += xv * w0.z; acc[3] += xv * w0.w;
    acc[4] += xv * w1.x; acc[5] += xv * w1.y; acc[6] += xv * w1.z; acc[7] += xv * w1.w;
  }
#pragma unroll
  for (int off = 32; off > 0; off >>= 1)
#pragma unroll
    for (int e = 0; e < 8; ++e) acc[e] += __shfl_xor(acc[e], off, 64);
  if (lane == 0) {
    float gv = grad[n];
    float lg[8];
#pragma unroll
    for (int e = 0; e < 8; ++e) lg[e] = acc[e] + gv * Wr[HD * NE + e] + br[e];
    float m = lg[0];
#pragma unroll
    for (int e = 1; e < 8; ++e) m = fmaxf(m, lg[e]);
    float s = 0.f, p[8];
#pragma unroll
    for (int e = 0; e < 8; ++e) { p[e] = expf(lg[e] - m); s += p[e]; }
    int i1 = 0;
#pragma unroll
    for (int e = 1; e < 8; ++e) if (lg[e] > lg[i1]) i1 = e;
    int i2 = (i1 == 0) ? 1 : 0;
#pragma unroll
    for (int e = 0; e < 8; ++e) if (e != i1 && lg[e] > lg[i2]) i2 = e;
    float inv = 1.0f / s;
    int p1 = atomicAdd(&counts[i1], 1);
    tokL[i1 * NTOK + p1] = n; wL[i1 * NTOK + p1] = p[i1] * inv;
    int p2 = atomicAdd(&counts[i2], 1);
    tokL[i2 * NTOK + p2] = n; wL[i2 * NTOK + p2] = p[i2] * inv;
  }
}

__global__ void prefix_k(const int* __restrict__ counts, int* __restrict__ base) {
  if (threadIdx.x == 0) {
    int s = 0;
    for (int e = 0; e < NE; ++e) { base[e] = s; s += counts[e]; }
  }
}

// ======== shared 8-phase machinery (Gray-code operand reuse) ========
// LDS buffer p at p*65536: [A-half0|A-half1|B-half0|B-half1], 16KB each.
// Per buffer, 4 phases walk quadrants (0,0)->(0,1)->(1,1)->(1,0); only the
// changed operand-half is re-read from LDS (af reload on MH change; bf0/bf1
// hold B-half0/B-half1 fragments across the group).

#define DSA(BUF, MH)                                                          \
  {                                                                           \
    const char* _ab = smem + (BUF)*65536 + (MH)*16384;                        \
    _Pragma("unroll") for (int mf = 0; mf < 4; ++mf) {                        \
      int row = wm * 64 + mf * 16 + lr;                                       \
      _Pragma("unroll") for (int k2 = 0; k2 < 2; ++k2) {                      \
        int off = row * 128 + ((k2 * 64 + (lk << 4)) ^ ((row & 7) << 4));     \
        af[mf][k2] = *(const half8*)(_ab + off);                              \
      }                                                                       \
    }                                                                         \
  }

#define DSB(BUF, NH, BF)                                                      \
  {                                                                           \
    const char* _bb = smem + (BUF)*65536 + 32768 + (NH)*16384;                \
    _Pragma("unroll") for (int nf = 0; nf < 2; ++nf) {                        \
      int row = wn * 32 + nf * 16 + lr;                                       \
      _Pragma("unroll") for (int k2 = 0; k2 < 2; ++k2) {                      \
        int off = row * 128 + ((k2 * 64 + (lk << 4)) ^ ((row & 7) << 4));     \
        BF[nf][k2] = *(const half8*)(_bb + off);                              \
      }                                                                       \
    }                                                                         \
  }

#define MFMAQ(MH, NH, BF)                                                     \
  __builtin_amdgcn_s_setprio(1);                                              \
  _Pragma("unroll") for (int mf = 0; mf < 4; ++mf)                            \
  _Pragma("unroll") for (int nf = 0; nf < 2; ++nf)                            \
  _Pragma("unroll") for (int k2 = 0; k2 < 2; ++k2)                            \
    acc[(MH)*4 + mf][(NH)*2 + nf] = __builtin_amdgcn_mfma_f32_16x16x32_f16(   \
        af[mf][k2], BF[nf][k2], acc[(MH)*4 + mf][(NH)*2 + nf], 0, 0, 0);      \
  __builtin_amdgcn_s_setprio(0);

#define PH(DS, MH, NH, BF, STG, VM)                                           \
  do {                                                                        \
    DS;                                                                       \
    STG;                                                                      \
    if (VM) asm volatile("s_waitcnt vmcnt(4)" ::: "memory");                  \
    __builtin_amdgcn_s_barrier();                                             \
    asm volatile("s_waitcnt lgkmcnt(0)" ::: "memory");                        \
    MFMAQ(MH, NH, BF);                                                        \
    __builtin_amdgcn_s_barrier();                                             \
  } while (0)

// stage one half-tile (128 rows x 64 k f16 = 16KB) = 2 gload16 per thread
#define STAGE_A(BUF, H, KIDX)                                                 \
  {                                                                           \
    char* _d = smem + (BUF)*65536 + (H)*16384 + (wid << 10);                  \
    gload16(aP[(H)*2 + 0] + (KIDX)*64, _d);                                   \
    gload16(aP[(H)*2 + 1] + (KIDX)*64, _d + 8192);                            \
  }
#define STAGE_B(BUF, H, KIDX, LDB)                                            \
  {                                                                           \
    char* _d = smem + (BUF)*65536 + 32768 + (H)*16384 + (wid << 10);          \
    gload16(bP + (size_t)((H)*128) * (LDB) + (KIDX)*64, _d);                  \
    gload16(bP + (size_t)((H)*128 + 64) * (LDB) + (KIDX)*64, _d + 8192);      \
  }

// one full iteration = 2 K-tiles (buf0 then buf1), Gray-code phases
#define ITER8(T1, T0N, T1N, LDB)                                              \
  PH(DSA(0, 0); DSB(0, 0, bf0), 0, 0, bf0, STAGE_A(1, 1, T1), 0);             \
  PH(DSB(0, 1, bf1),            0, 1, bf1, STAGE_B(1, 0, T1, LDB), 0);        \
  PH(DSA(0, 1),                 1, 1, bf1, STAGE_A(0, 0, T0N), 0);            \
  PH(,                          1, 0, bf0, STAGE_B(0, 1, T0N, LDB), 1);       \
  PH(DSA(1, 0); DSB(1, 0, bf0), 0, 0, bf0, STAGE_A(0, 1, T0N), 0);            \
  PH(DSB(1, 1, bf1),            0, 1, bf1, STAGE_B(0, 0, T0N, LDB), 0);       \
  PH(DSA(1, 1),                 1, 1, bf1, STAGE_A(1, 0, T1N), 0);            \
  PH(,                          1, 0, bf0, STAGE_B(1, 1, T1N, LDB), 1);

// ---------------- GEMM1: h = gelu(Xg @ W1 + b1) ----------------
__global__ __launch_bounds__(512, 2) void gemm1_k(const _Float16* __restrict__ xh,
                                                  const _Float16* __restrict__ w1t,
                                                  const float* __restrict__ b1,
                                                  const int* __restrict__ tokL,
                                                  const int* __restrict__ counts,
                                                  const int* __restrict__ base,
                                                  _Float16* __restrict__ hbuf) {
  int e, m0, cnt;
  if (!tile_lookup(counts, blockIdx.y, e, m0, cnt)) return;
  const int n0 = blockIdx.x * 256;
  const int hb = base[e];

  __shared__ __align__(16) char smem[131072];

  const int tid = threadIdx.x;
  const int lane = tid & 63;
  const int wid = tid >> 6;
  const int wm = wid & 1, wn = wid >> 1;
  const int lr = lane & 15, lk = lane >> 4;

  const int srow = tid >> 3;                       // 0..63
  const int kk = ((tid & 7) ^ (srow & 7)) << 3;    // swizzled f16 k-chunk
  const _Float16* aP[4];
#pragma unroll
  for (int h = 0; h < 2; ++h)
#pragma unroll
    for (int j = 0; j < 2; ++j) {
      int r = h * 128 + j * 64 + srow;
      int gm = m0 + r; if (gm >= cnt) gm = cnt - 1;
      aP[h * 2 + j] = xh + (size_t)tokL[e * NTOK + gm] * HD + kk;
    }
  const _Float16* bP = w1t + ((size_t)e * FF + n0 + srow) * HD + kk;

  f32x4 acc[8][4] = {};
  half8 af[4][2], bf0[2][2], bf1[2][2];

  // prologue: full tile0 -> L0; A-half0,B-half1 of tile1 -> L1
  STAGE_A(0, 0, 0); STAGE_A(0, 1, 0); STAGE_B(0, 0, 0, HD); STAGE_B(0, 1, 0, HD);
  STAGE_A(1, 0, 1); STAGE_B(1, 1, 1, HD);
  asm volatile("s_waitcnt vmcnt(4)" ::: "memory");
  __builtin_amdgcn_s_barrier();

  const int NK = HD / 64;          // 16 K-tiles
  for (int it = 0; it < NK / 2; ++it) {
    int t1 = 2 * it + 1;
    int t0n = 2 * it + 2; if (t0n > NK - 1) t0n = NK - 1;
    int t1n = 2 * it + 3; if (t1n > NK - 1) t1n = NK - 1;
    ITER8(t1, t0n, t1n, HD);
  }
  asm volatile("s_waitcnt vmcnt(0) lgkmcnt(0)" ::: "memory");
  __builtin_amdgcn_s_barrier();

  // epilogue: bias + exact-erf GELU -> swizzled LDS bounce -> coalesced half8 stores
#pragma unroll
  for (int ni = 0; ni < 4; ++ni) {
    const int nh = ni >> 1, nf = ni & 1;
    int col = nh * 128 + wn * 32 + nf * 16 + lr;
    float bias = b1[(size_t)e * FF + n0 + col];
#pragma unroll
    for (int mi = 0; mi < 8; ++mi) {
      const int mh = mi >> 2, mf = mi & 3;
      int rb = mh * 128 + wm * 64 + mf * 16 + lk * 4;
#pragma unroll
      for (int j = 0; j < 4; ++j) {
        float v = acc[mi][ni][j] + bias;
        v = 0.5f * v * (1.0f + erff(v * 0.70710678118654752f));
        int row = rb + j;
        *(_Float16*)(smem + row * 512 + ((col * 2) ^ ((row & 7) << 4))) = (_Float16)v;
      }
    }
  }
  asm volatile("s_waitcnt lgkmcnt(0)" ::: "memory");
  __builtin_amdgcn_s_barrier();
#pragma unroll
  for (int ps = 0; ps < 16; ++ps) {
    int row = ps * 16 + (tid >> 5);
    int c = tid & 31;
    int lc = c ^ (row & 7);
    half8 v = *(const half8*)(smem + row * 512 + c * 16);
    int gm = m0 + row;
    if (gm < cnt)
      *(half8*)(hbuf + (size_t)(hb + gm) * FF + n0 + lc * 8) = v;
  }
}

// ---------------- GEMM2: out += p * (h @ W2 + b2), K-split x2, atomic scatter ----------------
__global__ __launch_bounds__(512, 2) void gemm2_k(const _Float16* __restrict__ hbuf,
                                                  const _Float16* __restrict__ w2t,
                                                  const float* __restrict__ b2,
                                                  const int* __restrict__ tokL,
                                                  const float* __restrict__ wL,
                                                  const int* __restrict__ counts,
                                                  const int* __restrict__ base,
                                                  float* __restrict__ out) {
  int e, m0, cnt;
  if (!tile_lookup(counts, blockIdx.y, e, m0, cnt)) return;
  const int n0 = blockIdx.x * 256;
  const int ks = blockIdx.z;             // K-split half: k in [ks*2048, ks*2048+2048)
  const int hb = base[e];

  __shared__ __align__(16) char smem[131072];

  const int tid = threadIdx.x;
  const int lane = tid & 63;
  const int wid = tid >> 6;
  const int wm = wid & 1, wn = wid >> 1;
  const int lr = lane & 15, lk = lane >> 4;

  const int srow = tid >> 3;
  const int kk = ((tid & 7) ^ (srow & 7)) << 3;
  const size_t kbase = (size_t)ks * 2048;
  const _Float16* aP[4];
#pragma unroll
  for (int h = 0; h < 2; ++h)
#pragma unroll
    for (int j = 0; j < 2; ++j) {
      int r = h * 128 + j * 64 + srow;
      int gm = m0 + r; if (gm >= cnt) gm = cnt - 1;
      aP[h * 2 + j] = hbuf + (size_t)(hb + gm) * FF + kbase + kk;
    }
  const _Float16* bP = w2t + ((size_t)e * HD + n0 + srow) * FF + kbase + kk;

  f32x4 acc[8][4] = {};
  half8 af[4][2], bf0[2][2], bf1[2][2];

  STAGE_A(0, 0, 0); STAGE_A(0, 1, 0); STAGE_B(0, 0, 0, FF); STAGE_B(0, 1, 0, FF);
  STAGE_A(1, 0, 1); STAGE_B(1, 1, 1, FF);
  asm volatile("s_waitcnt vmcnt(4)" ::: "memory");
  __builtin_amdgcn_s_barrier();

  const int NK = 2048 / 64;        // 32 K-tiles per split half
  for (int it = 0; it < NK / 2; ++it) {
    int t1 = 2 * it + 1;
    int t0n = 2 * it + 2; if (t0n > NK - 1) t0n = NK - 1;
    int t1n = 2 * it + 3; if (t1n > NK - 1) t1n = NK - 1;
    ITER8(t1, t0n, t1n, FF);
  }
  asm volatile("s_waitcnt vmcnt(0) lgkmcnt(0)" ::: "memory");
  __builtin_amdgcn_s_barrier();

  // epilogue: p * (acc [+ b2 if ks==0]) atomically scattered to out[token][n]
  float b2v[4];
#pragma unroll
  for (int ni = 0; ni < 4; ++ni) {
    const int nh = ni >> 1, nf = ni & 1;
    int n = n0 + nh * 128 + wn * 32 + nf * 16 + lr;
    b2v[ni] = (ks == 0) ? b2[(size_t)e * HD + n] : 0.0f;
  }
#pragma unroll
  for (int mi = 0; mi < 8; ++mi) {
    const int mh = mi >> 2, mf = mi & 3;
    int rb = m0 + mh * 128 + wm * 64 + mf * 16 + lk * 4;
    int tk[4]; float pw[4]; bool ok[4];
#pragma unroll
    for (int j = 0; j < 4; ++j) {
      int gm = rb + j;
      ok[j] = (gm < cnt);
      int idx = e * NTOK + (ok[j] ? gm : 0);
      tk[j] = tokL[idx];
      pw[j] = wL[idx];
    }
#pragma unroll
    for (int ni = 0; ni < 4; ++ni) {
      const int nh = ni >> 1, nf = ni & 1;
      int n = n0 + nh * 128 + wn * 32 + nf * 16 + lr;
#pragma unroll
      for (int j = 0; j < 4; ++j) {
        if (ok[j])
          atomicAdd(out + (size_t)tk[j] * HD + n, pw[j] * (acc[mi][ni][j] + b2v[ni]));
      }
    }
  }
}

// ---------------- launch ----------------
extern "C" void kernel_launch(void* const* d_in, const int* in_sizes, int n_in,
                              void* d_out, int out_size, void* d_ws, size_t ws_size,
                              hipStream_t stream) {
  const float* x    = (const float*)d_in[0];
  const float* grad = (const float*)d_in[1];
  const float* Wr   = (const float*)d_in[2];
  const float* br   = (const float*)d_in[3];
  const float* W1   = (const float*)d_in[4];
  const float* b1   = (const float*)d_in[5];
  const float* W2   = (const float*)d_in[6];
  const float* b2   = (const float*)d_in[7];
  float* out = (float*)d_out;

  char* ws = (char*)d_ws;
  int*      counts = (int*)(ws + 0);
  int*      basep  = (int*)(ws + 128);
  int*      tokL   = (int*)(ws + 256);
  float*    wL     = (float*)(ws + 262400);
  _Float16* xh     = (_Float16*)(ws + 524544);
  _Float16* w1t    = (_Float16*)(ws + 17301760);
  _Float16* w2t    = (_Float16*)(ws + 84410624);
  _Float16* hbuf   = (_Float16*)(ws + 151519488);   // end = 285737216
  if (ws_size < 285737216ull) return;

  hipMemsetAsync(counts, 0, 64, stream);
  hipMemsetAsync(out, 0, (size_t)NTOK * HD * 4, stream);

  transc_k<<<dim3(FF / 64, HD / 64, NE), 256, 0, stream>>>(W1, w1t, HD, FF);
  transc_k<<<dim3(HD / 64, FF / 64, NE), 256, 0, stream>>>(W2, w2t, FF, HD);
  router_k<<<NTOK / 4, 256, 0, stream>>>(x, grad, Wr, br, counts, tokL, wL, xh);
  prefix_k<<<1, 64, 0, stream>>>(counts, basep);

  gemm1_k<<<dim3(FF / 256, MAXT), 512, 0, stream>>>(xh, w1t, b1, tokL, counts, basep, hbuf);
  gemm2_k<<<dim3(HD / 256, MAXT, 2), 512, 0, stream>>>(hbuf, w2t, b2, tokL, wL, counts, basep, out);
}

// Round 7
// 860.563 us; speedup vs baseline: 1.3862x; 1.1873x over previous
//
#include <hip/hip_runtime.h>
#include <hip/hip_bf16.h>
#include <stdint.h>

// Sparse MoE: N=8192 tokens, H=1024, E=8 experts, top-K=2, FF=4096.
// router(top2, no atomics) -> LDS-histogram list build -> grouped f16 MFMA
// GEMMs (256x256 8-wave 8-phase counted-vmcnt, Gray-code reuse, XCD swizzle)
// -> per-row obuf (aliases w1t region; stride-bug fixed) -> gather.

#define NTOK 8192
#define HD   1024
#define NE   8
#define FF   4096
#define MAXT 72    // max total 256-row m-tiles: sum(ceil(cnt_e/256)) <= 64+8
#define OBHALF ((size_t)NTOK * 2 * HD)   // 16777216 elements per K-split half

typedef float  f32x4 __attribute__((ext_vector_type(4)));
typedef _Float16 half8 __attribute__((ext_vector_type(8)));
typedef _Float16 half4 __attribute__((ext_vector_type(4)));

#define AS1 __attribute__((address_space(1)))
#define AS3 __attribute__((address_space(3)))

__device__ __forceinline__ void gload16(const void* g, void* l) {
  __builtin_amdgcn_global_load_lds((AS1 void*)g, (AS3 void*)l, 16, 0, 0);
}

// global 256-row tile index -> (expert, m0, cnt)
__device__ __forceinline__ bool tile_lookup(const int* __restrict__ counts,
                                            int t, int& e, int& m0, int& cnt) {
#pragma unroll
  for (int i = 0; i < NE; ++i) {
    int c = counts[i];
    int nt = (c + 255) >> 8;
    if (t < nt) { e = i; m0 = t << 8; cnt = c; return true; }
    t -= nt;
  }
  return false;
}

// ---------------- prep: convert + transpose weights ----------------
// src: [E][R][C] f32 row-major  ->  dst: [E][C][R] f16 row-major
__global__ __launch_bounds__(256) void transc_k(const float* __restrict__ src,
                                                _Float16* __restrict__ dst,
                                                int R, int C) {
  __shared__ float t[64][65];
  const int e = blockIdx.z;
  const size_t eb = (size_t)e * R * C;
  const int r0 = blockIdx.y * 64, c0 = blockIdx.x * 64;
  const int tid = threadIdx.x;
#pragma unroll
  for (int i = 0; i < 4; ++i) {
    int idx = tid + i * 256;
    int r = idx >> 4, c = (idx & 15) * 4;
    float4 v = *(const float4*)(src + eb + (size_t)(r0 + r) * C + (c0 + c));
    t[r][c] = v.x; t[r][c + 1] = v.y; t[r][c + 2] = v.z; t[r][c + 3] = v.w;
  }
  __syncthreads();
#pragma unroll
  for (int i = 0; i < 4; ++i) {
    int idx = tid + i * 256;
    int cr = idx >> 4, r4 = (idx & 15) * 4;
    half4 o = {(_Float16)t[r4][cr], (_Float16)t[r4 + 1][cr],
               (_Float16)t[r4 + 2][cr], (_Float16)t[r4 + 3][cr]};
    *(half4*)(dst + eb + (size_t)(c0 + cr) * R + (r0 + r4)) = o;
  }
}

// ---------------- router: top-2 per token, NO atomics (+ fused x->f16) ----------------
__global__ __launch_bounds__(256) void router_k(const float* __restrict__ x,
                                                const float* __restrict__ grad,
                                                const float* __restrict__ Wr,
                                                const float* __restrict__ br,
                                                int2* __restrict__ te,
                                                float2* __restrict__ tp,
                                                _Float16* __restrict__ xh) {
  const int lane = threadIdx.x & 63;
  const int n = blockIdx.x * 4 + (threadIdx.x >> 6);
  float acc[8] = {0.f, 0.f, 0.f, 0.f, 0.f, 0.f, 0.f, 0.f};
  const float* xr = x + (size_t)n * HD;
  _Float16* xo = xh + (size_t)n * HD;
#pragma unroll 4
  for (int i = 0; i < 16; ++i) {
    float xv = xr[i * 64 + lane];
    xo[i * 64 + lane] = (_Float16)xv;            // fused convx
    const float* wr = Wr + (size_t)(i * 64 + lane) * NE;
    float4 w0 = *(const float4*)wr;
    float4 w1 = *(const float4*)(wr + 4);
    acc[0] += xv * w0.x; acc[1] += xv * w0.y; acc[2] += xv * w0.z; acc[3] += xv * w0.w;
    acc[4] += xv * w1.x; acc[5] += xv * w1.y; acc[6] += xv * w1.z; acc[7] += xv * w1.w;
  }
#pragma unroll
  for (int off = 32; off > 0; off >>= 1)
#pragma unroll
    for (int e = 0; e < 8; ++e) acc[e] += __shfl_xor(acc[e], off, 64);
  if (lane == 0) {
    float gv = grad[n];
    float lg[8];
#pragma unroll
    for (int e = 0; e < 8; ++e) lg[e] = acc[e] + gv * Wr[HD * NE + e] + br[e];
    float m = lg[0];
#pragma unroll
    for (int e = 1; e < 8; ++e) m = fmaxf(m, lg[e]);
    float s = 0.f, p[8];
#pragma unroll
    for (int e = 0; e < 8; ++e) { p[e] = expf(lg[e] - m); s += p[e]; }
    int i1 = 0;
#pragma unroll
    for (int e = 1; e < 8; ++e) if (lg[e] > lg[i1]) i1 = e;
    int i2 = (i1 == 0) ? 1 : 0;
#pragma unroll
    for (int e = 0; e < 8; ++e) if (e != i1 && lg[e] > lg[i2]) i2 = e;
    float inv = 1.0f / s;
    te[n] = make_int2(i1, i2);
    tp[n] = make_float2(p[i1] * inv, p[i2] * inv);
  }
}

// ---------------- list build: LDS histogram, 8 global atomics per block ----------------
__global__ __launch_bounds__(256) void build_k(const int2* __restrict__ te,
                                               int* __restrict__ counts,
                                               int* __restrict__ tokL,
                                               int2* __restrict__ rowPos) {
  __shared__ int hist[NE], cursor[NE], gbase[NE];
  const int t = threadIdx.x;
  if (t < NE) { hist[t] = 0; cursor[t] = 0; }
  __syncthreads();
  const int n = blockIdx.x * 256 + t;
  int2 e = te[n];
  atomicAdd(&hist[e.x], 1);
  atomicAdd(&hist[e.y], 1);
  __syncthreads();
  if (t < NE) gbase[t] = atomicAdd(&counts[t], hist[t]);
  __syncthreads();
  int p1 = gbase[e.x] + atomicAdd(&cursor[e.x], 1);
  tokL[e.x * NTOK + p1] = n;
  int p2 = gbase[e.y] + atomicAdd(&cursor[e.y], 1);
  tokL[e.y * NTOK + p2] = n;
  rowPos[n] = make_int2(p1, p2);
}

__global__ void prefix_k(const int* __restrict__ counts, int* __restrict__ base) {
  if (threadIdx.x == 0) {
    int s = 0;
    for (int e = 0; e < NE; ++e) { base[e] = s; s += counts[e]; }
  }
}

// ======== shared 8-phase machinery (Gray-code operand reuse) ========
#define DSA(BUF, MH)                                                          \
  {                                                                           \
    const char* _ab = smem + (BUF)*65536 + (MH)*16384;                        \
    _Pragma("unroll") for (int mf = 0; mf < 4; ++mf) {                        \
      int row = wm * 64 + mf * 16 + lr;                                       \
      _Pragma("unroll") for (int k2 = 0; k2 < 2; ++k2) {                      \
        int off = row * 128 + ((k2 * 64 + (lk << 4)) ^ ((row & 7) << 4));     \
        af[mf][k2] = *(const half8*)(_ab + off);                              \
      }                                                                       \
    }                                                                         \
  }

#define DSB(BUF, NH, BF)                                                      \
  {                                                                           \
    const char* _bb = smem + (BUF)*65536 + 32768 + (NH)*16384;                \
    _Pragma("unroll") for (int nf = 0; nf < 2; ++nf) {                        \
      int row = wn * 32 + nf * 16 + lr;                                       \
      _Pragma("unroll") for (int k2 = 0; k2 < 2; ++k2) {                      \
        int off = row * 128 + ((k2 * 64 + (lk << 4)) ^ ((row & 7) << 4));     \
        BF[nf][k2] = *(const half8*)(_bb + off);                              \
      }                                                                       \
    }                                                                         \
  }

#define MFMAQ(MH, NH, BF)                                                     \
  __builtin_amdgcn_s_setprio(1);                                              \
  _Pragma("unroll") for (int mf = 0; mf < 4; ++mf)                            \
  _Pragma("unroll") for (int nf = 0; nf < 2; ++nf)                            \
  _Pragma("unroll") for (int k2 = 0; k2 < 2; ++k2)                            \
    acc[(MH)*4 + mf][(NH)*2 + nf] = __builtin_amdgcn_mfma_f32_16x16x32_f16(   \
        af[mf][k2], BF[nf][k2], acc[(MH)*4 + mf][(NH)*2 + nf], 0, 0, 0);      \
  __builtin_amdgcn_s_setprio(0);

#define PH(DS, MH, NH, BF, STG, VM)                                           \
  do {                                                                        \
    DS;                                                                       \
    STG;                                                                      \
    if (VM) asm volatile("s_waitcnt vmcnt(4)" ::: "memory");                  \
    __builtin_amdgcn_s_barrier();                                             \
    asm volatile("s_waitcnt lgkmcnt(0)" ::: "memory");                        \
    MFMAQ(MH, NH, BF);                                                        \
    __builtin_amdgcn_s_barrier();                                             \
  } while (0)

#define STAGE_A(BUF, H, KIDX)                                                 \
  {                                                                           \
    char* _d = smem + (BUF)*65536 + (H)*16384 + (wid << 10);                  \
    gload16(aP[(H)*2 + 0] + (KIDX)*64, _d);                                   \
    gload16(aP[(H)*2 + 1] + (KIDX)*64, _d + 8192);                            \
  }
#define STAGE_B(BUF, H, KIDX, LDB)                                            \
  {                                                                           \
    char* _d = smem + (BUF)*65536 + 32768 + (H)*16384 + (wid << 10);          \
    gload16(bP + (size_t)((H)*128) * (LDB) + (KIDX)*64, _d);                  \
    gload16(bP + (size_t)((H)*128 + 64) * (LDB) + (KIDX)*64, _d + 8192);      \
  }

#define ITER8(T1, T0N, T1N, LDB)                                              \
  PH(DSA(0, 0); DSB(0, 0, bf0), 0, 0, bf0, STAGE_A(1, 1, T1), 0);             \
  PH(DSB(0, 1, bf1),            0, 1, bf1, STAGE_B(1, 0, T1, LDB), 0);        \
  PH(DSA(0, 1),                 1, 1, bf1, STAGE_A(0, 0, T0N), 0);            \
  PH(,                          1, 0, bf0, STAGE_B(0, 1, T0N, LDB), 1);       \
  PH(DSA(1, 0); DSB(1, 0, bf0), 0, 0, bf0, STAGE_A(0, 1, T0N), 0);            \
  PH(DSB(1, 1, bf1),            0, 1, bf1, STAGE_B(0, 0, T0N, LDB), 0);       \
  PH(DSA(1, 1),                 1, 1, bf1, STAGE_A(1, 0, T1N), 0);            \
  PH(,                          1, 0, bf0, STAGE_B(1, 1, T1N, LDB), 1);

// ---------------- GEMM1: h = gelu(Xg @ W1 + b1) ----------------
__global__ __launch_bounds__(512, 2) void gemm1_k(const _Float16* __restrict__ xh,
                                                  const _Float16* __restrict__ w1t,
                                                  const float* __restrict__ b1,
                                                  const int* __restrict__ tokL,
                                                  const int* __restrict__ counts,
                                                  const int* __restrict__ base,
                                                  _Float16* __restrict__ hbuf) {
  // XCD-chunked bijective swizzle: nwg = 16*72 = 1152, 144 per XCD
  const int flat = blockIdx.x + (blockIdx.y << 4);
  const int wg = (flat & 7) * 144 + (flat >> 3);
  int e, m0, cnt;
  if (!tile_lookup(counts, wg >> 4, e, m0, cnt)) return;
  const int n0 = (wg & 15) * 256;
  const int hb = base[e];

  __shared__ __align__(16) char smem[131072];

  const int tid = threadIdx.x;
  const int lane = tid & 63;
  const int wid = tid >> 6;
  const int wm = wid & 1, wn = wid >> 1;
  const int lr = lane & 15, lk = lane >> 4;

  const int srow = tid >> 3;
  const int kk = ((tid & 7) ^ (srow & 7)) << 3;
  const _Float16* aP[4];
#pragma unroll
  for (int h = 0; h < 2; ++h)
#pragma unroll
    for (int j = 0; j < 2; ++j) {
      int r = h * 128 + j * 64 + srow;
      int gm = m0 + r; if (gm >= cnt) gm = cnt - 1;
      aP[h * 2 + j] = xh + (size_t)tokL[e * NTOK + gm] * HD + kk;
    }
  const _Float16* bP = w1t + ((size_t)e * FF + n0 + srow) * HD + kk;

  f32x4 acc[8][4] = {};
  half8 af[4][2], bf0[2][2], bf1[2][2];

  STAGE_A(0, 0, 0); STAGE_A(0, 1, 0); STAGE_B(0, 0, 0, HD); STAGE_B(0, 1, 0, HD);
  STAGE_A(1, 0, 1); STAGE_B(1, 1, 1, HD);
  asm volatile("s_waitcnt vmcnt(4)" ::: "memory");
  __builtin_amdgcn_s_barrier();

  const int NK = HD / 64;
  for (int it = 0; it < NK / 2; ++it) {
    int t1 = 2 * it + 1;
    int t0n = 2 * it + 2; if (t0n > NK - 1) t0n = NK - 1;
    int t1n = 2 * it + 3; if (t1n > NK - 1) t1n = NK - 1;
    ITER8(t1, t0n, t1n, HD);
  }
  asm volatile("s_waitcnt vmcnt(0) lgkmcnt(0)" ::: "memory");
  __builtin_amdgcn_s_barrier();

  // epilogue: bias + exact-erf GELU -> swizzled LDS bounce -> half8 stores
#pragma unroll
  for (int ni = 0; ni < 4; ++ni) {
    const int nh = ni >> 1, nf = ni & 1;
    int col = nh * 128 + wn * 32 + nf * 16 + lr;
    float bias = b1[(size_t)e * FF + n0 + col];
#pragma unroll
    for (int mi = 0; mi < 8; ++mi) {
      const int mh = mi >> 2, mf = mi & 3;
      int rb = mh * 128 + wm * 64 + mf * 16 + lk * 4;
#pragma unroll
      for (int j = 0; j < 4; ++j) {
        float v = acc[mi][ni][j] + bias;
        v = 0.5f * v * (1.0f + erff(v * 0.70710678118654752f));
        int row = rb + j;
        *(_Float16*)(smem + row * 512 + ((col * 2) ^ ((row & 7) << 4))) = (_Float16)v;
      }
    }
  }
  asm volatile("s_waitcnt lgkmcnt(0)" ::: "memory");
  __builtin_amdgcn_s_barrier();
#pragma unroll
  for (int ps = 0; ps < 16; ++ps) {
    int row = ps * 16 + (tid >> 5);
    int c = tid & 31;
    int lc = c ^ (row & 7);
    half8 v = *(const half8*)(smem + row * 512 + c * 16);
    int gm = m0 + row;
    if (gm < cnt)
      *(half8*)(hbuf + (size_t)(hb + gm) * FF + n0 + lc * 8) = v;
  }
}

// ---------------- GEMM2: obuf[ks] rows = h @ W2 (half-K), f16, no atomics ----------------
__global__ __launch_bounds__(512, 2) void gemm2_k(const _Float16* __restrict__ hbuf,
                                                  const _Float16* __restrict__ w2t,
                                                  const int* __restrict__ counts,
                                                  const int* __restrict__ base,
                                                  _Float16* __restrict__ obuf) {
  // XCD-chunked swizzle: nwg per z-slice = 4*72 = 288, 36 per XCD
  const int flat = blockIdx.x + (blockIdx.y << 2);
  const int wg = (flat & 7) * 36 + (flat >> 3);
  int e, m0, cnt;
  if (!tile_lookup(counts, wg >> 2, e, m0, cnt)) return;
  const int n0 = (wg & 3) * 256;
  const int ks = blockIdx.z;             // K half: [ks*2048, ks*2048+2048)
  const int hb = base[e];

  __shared__ __align__(16) char smem[131072];

  const int tid = threadIdx.x;
  const int lane = tid & 63;
  const int wid = tid >> 6;
  const int wm = wid & 1, wn = wid >> 1;
  const int lr = lane & 15, lk = lane >> 4;

  const int srow = tid >> 3;
  const int kk = ((tid & 7) ^ (srow & 7)) << 3;
  const size_t kbase = (size_t)ks * 2048;
  const _Float16* aP[4];
#pragma unroll
  for (int h = 0; h < 2; ++h)
#pragma unroll
    for (int j = 0; j < 2; ++j) {
      int r = h * 128 + j * 64 + srow;
      int gm = m0 + r; if (gm >= cnt) gm = cnt - 1;
      aP[h * 2 + j] = hbuf + (size_t)(hb + gm) * FF + kbase + kk;
    }
  const _Float16* bP = w2t + ((size_t)e * HD + n0 + srow) * FF + kbase + kk;

  f32x4 acc[8][4] = {};
  half8 af[4][2], bf0[2][2], bf1[2][2];

  STAGE_A(0, 0, 0); STAGE_A(0, 1, 0); STAGE_B(0, 0, 0, FF); STAGE_B(0, 1, 0, FF);
  STAGE_A(1, 0, 1); STAGE_B(1, 1, 1, FF);
  asm volatile("s_waitcnt vmcnt(4)" ::: "memory");
  __builtin_amdgcn_s_barrier();

  const int NK = 2048 / 64;
  for (int it = 0; it < NK / 2; ++it) {
    int t1 = 2 * it + 1;
    int t0n = 2 * it + 2; if (t0n > NK - 1) t0n = NK - 1;
    int t1n = 2 * it + 3; if (t1n > NK - 1) t1n = NK - 1;
    ITER8(t1, t0n, t1n, FF);
  }
  asm volatile("s_waitcnt vmcnt(0) lgkmcnt(0)" ::: "memory");
  __builtin_amdgcn_s_barrier();

  // epilogue: acc -> f16 rows of obuf[ks] via swizzled LDS bounce
  _Float16* ob = obuf + (size_t)ks * OBHALF;   // FIXED: full 16777216-elem half-stride
#pragma unroll
  for (int ni = 0; ni < 4; ++ni) {
    const int nh = ni >> 1, nf = ni & 1;
    int col = nh * 128 + wn * 32 + nf * 16 + lr;
#pragma unroll
    for (int mi = 0; mi < 8; ++mi) {
      const int mh = mi >> 2, mf = mi & 3;
      int rb = mh * 128 + wm * 64 + mf * 16 + lk * 4;
#pragma unroll
      for (int j = 0; j < 4; ++j) {
        int row = rb + j;
        *(_Float16*)(smem + row * 512 + ((col * 2) ^ ((row & 7) << 4))) =
            (_Float16)acc[mi][ni][j];
      }
    }
  }
  asm volatile("s_waitcnt lgkmcnt(0)" ::: "memory");
  __builtin_amdgcn_s_barrier();
#pragma unroll
  for (int ps = 0; ps < 16; ++ps) {
    int row = ps * 16 + (tid >> 5);
    int c = tid & 31;
    int lc = c ^ (row & 7);
    half8 v = *(const half8*)(smem + row * 512 + c * 16);
    int gm = m0 + row;
    if (gm < cnt)
      *(half8*)(ob + (size_t)(hb + gm) * HD + n0 + lc * 8) = v;
  }
}

// ---------------- gather: out[n] = sum_k p_k * (obuf rows + b2), plain stores ----------------
__global__ __launch_bounds__(512) void gather_k(const int2* __restrict__ te,
                                                const float2* __restrict__ tp,
                                                const int2* __restrict__ rowPos,
                                                const int* __restrict__ base,
                                                const float* __restrict__ b2,
                                                const _Float16* __restrict__ obuf,
                                                float* __restrict__ out) {
  const int lane = threadIdx.x & 63;
  const int n = blockIdx.x * 8 + (threadIdx.x >> 6);
  const int2 e = te[n];
  const float2 p = tp[n];
  const int2 rp = rowPos[n];
  const size_t r1 = (size_t)(base[e.x] + rp.x) * HD;
  const size_t r2 = (size_t)(base[e.y] + rp.y) * HD;
  const int c = lane * 16;
  const _Float16* a1 = obuf + r1 + c;
  const _Float16* a2 = obuf + r2 + c;
  const float* b2a = b2 + (size_t)e.x * HD + c;
  const float* b2b = b2 + (size_t)e.y * HD + c;
  float* o = out + (size_t)n * HD + c;
#pragma unroll
  for (int q = 0; q < 2; ++q) {
    half8 x10 = *(const half8*)(a1 + q * 8);
    half8 x11 = *(const half8*)(a1 + OBHALF + q * 8);
    half8 x20 = *(const half8*)(a2 + q * 8);
    half8 x21 = *(const half8*)(a2 + OBHALF + q * 8);
    float4 r0, r1v;
#pragma unroll
    for (int j = 0; j < 4; ++j) {
      ((float*)&r0)[j] = p.x * ((float)x10[j] + (float)x11[j] + b2a[q * 8 + j]) +
                         p.y * ((float)x20[j] + (float)x21[j] + b2b[q * 8 + j]);
      ((float*)&r1v)[j] = p.x * ((float)x10[j + 4] + (float)x11[j + 4] + b2a[q * 8 + j + 4]) +
                          p.y * ((float)x20[j + 4] + (float)x21[j + 4] + b2b[q * 8 + j + 4]);
    }
    *(float4*)(o + q * 8) = r0;
    *(float4*)(o + q * 8 + 4) = r1v;
  }
}

// ---------------- launch ----------------
extern "C" void kernel_launch(void* const* d_in, const int* in_sizes, int n_in,
                              void* d_out, int out_size, void* d_ws, size_t ws_size,
                              hipStream_t stream) {
  const float* x    = (const float*)d_in[0];
  const float* grad = (const float*)d_in[1];
  const float* Wr   = (const float*)d_in[2];
  const float* br   = (const float*)d_in[3];
  const float* W1   = (const float*)d_in[4];
  const float* b1   = (const float*)d_in[5];
  const float* W2   = (const float*)d_in[6];
  const float* b2   = (const float*)d_in[7];
  float* out = (float*)d_out;

  char* ws = (char*)d_ws;
  int*      counts = (int*)(ws + 0);
  int*      basep  = (int*)(ws + 128);
  int*      tokL   = (int*)(ws + 256);          // 256 KiB
  int2*     te     = (int2*)(ws + 262400);      // 64 KiB
  float2*   tp     = (float2*)(ws + 327936);    // 64 KiB
  int2*     rowPos = (int2*)(ws + 393472);      // 64 KiB
  _Float16* xh     = (_Float16*)(ws + 524544);      // 16 MiB
  _Float16* w1t    = (_Float16*)(ws + 17301760);    // 64 MiB
  _Float16* w2t    = (_Float16*)(ws + 84410624);    // 64 MiB
  _Float16* hbuf   = (_Float16*)(ws + 151519488);   // 128 MiB ; end = 285737216
  // obuf ALIASES w1t's 64 MiB region: w1t's last reader (gemm1) completes
  // before gemm2 writes obuf (stream-ordered). Keeps ws at the proven size.
  _Float16* obuf   = (_Float16*)(ws + 17301760);
  if (ws_size < 285737216ull) return;

  hipMemsetAsync(counts, 0, 64, stream);

  transc_k<<<dim3(FF / 64, HD / 64, NE), 256, 0, stream>>>(W1, w1t, HD, FF);
  transc_k<<<dim3(HD / 64, FF / 64, NE), 256, 0, stream>>>(W2, w2t, FF, HD);
  router_k<<<NTOK / 4, 256, 0, stream>>>(x, grad, Wr, br, te, tp, xh);
  build_k<<<NTOK / 256, 256, 0, stream>>>(te, counts, tokL, rowPos);
  prefix_k<<<1, 64, 0, stream>>>(counts, basep);

  gemm1_k<<<dim3(FF / 256, MAXT), 512, 0, stream>>>(xh, w1t, b1, tokL, counts, basep, hbuf);
  gemm2_k<<<dim3(HD / 256, MAXT, 2), 512, 0, stream>>>(hbuf, w2t, counts, basep, obuf);
  gather_k<<<NTOK / 8, 512, 0, stream>>>(te, tp, rowPos, basep, b2, obuf, out);
}